// Round 4
// baseline (1688.467 us; speedup 1.0000x reference)
//
#include <hip/hip_runtime.h>

static constexpr int NN  = 100000;   // nodes
static constexpr int NE  = 1600000;  // edges
static constexpr int NG  = 1000;     // graphs
static constexpr int D   = 64;       // D_IN = D_HID
static constexpr int DH  = 32;       // head hidden
static constexpr int DO  = 8;        // out dim
static constexpr int BKT = 128;      // nodes per bucket (7 bits)
static constexpr int NBK = (NN + BKT - 1) / BKT;     // 782
static constexpr int CHUNK = 4096;                   // edges per binning block
static constexpr int NCH = (NE + CHUNK - 1) / CHUNK; // 391
static_assert(BKT == 128, "shifts below assume 7-bit local index");

// deg[dst[i]]++ and cnt[batch[i]]++ in one pass
__global__ void k_count2(const int* __restrict__ dst, const int* __restrict__ batch,
                         int* __restrict__ deg, int* __restrict__ cnt) {
    int i = blockIdx.x * 256 + threadIdx.x;
    if (i < NE) atomicAdd(&deg[dst[i]], 1);
    if (i < NN) atomicAdd(&cnt[batch[i]], 1);
}

// per-bucket edge counts = sum of deg over the bucket's 128 nodes
__global__ void k_bucket_sum(const int* __restrict__ deg, int* __restrict__ bsum) {
    __shared__ int ws[2];
    int b = blockIdx.x;
    int i = b * BKT + threadIdx.x;          // 128 threads
    int v = (i < NN) ? deg[i] : 0;
    for (int o = 32; o; o >>= 1) v += __shfl_down(v, o);
    if ((threadIdx.x & 63) == 0) ws[threadIdx.x >> 6] = v;
    __syncthreads();
    if (threadIdx.x == 0) bsum[b] = ws[0] + ws[1];
}

// single-block exclusive scan of NBK bucket counts -> boffs (+NE sentinel), gcur copy
__global__ void k_scan(const int* __restrict__ bsum, int* __restrict__ boffs,
                       int* __restrict__ gcur) {
    __shared__ int s[1024];
    int t = threadIdx.x;
    int v = (t < NBK) ? bsum[t] : 0;
    s[t] = v;
    __syncthreads();
    for (int o = 1; o < 1024; o <<= 1) {
        int a = (t >= o) ? s[t - o] : 0;
        __syncthreads();
        s[t] += a;
        __syncthreads();
    }
    if (t < NBK) { int ex = s[t] - v; boffs[t] = ex; gcur[t] = ex; }
    if (t == 0) boffs[NBK] = NE;
}

__global__ void k_dinv(const int* __restrict__ deg, float* __restrict__ dinv) {
    int i = blockIdx.x * 256 + threadIdx.x;
    if (i < NN) dinv[i] = rsqrtf((float)(deg[i] + 1));
}

// two-phase binning: LDS histogram -> per-bucket range reservation -> scatter
// packed edge = src*128 + (dst & 127), grouped by bucket dst>>7
__global__ __launch_bounds__(512) void
k_bin(const int* __restrict__ src, const int* __restrict__ dst,
      int* __restrict__ gcur, int* __restrict__ ebuf) {
    __shared__ int lcnt[NBK];
    __shared__ int lbase[NBK];
    int t = threadIdx.x;
    long base = (long)blockIdx.x * CHUNK;
    for (int b = t; b < NBK; b += 512) lcnt[b] = 0;
    __syncthreads();
    int pk[8], bk[8], of[8];
#pragma unroll
    for (int j = 0; j < 8; ++j) {
        long i = base + j * 512 + t;
        if (i < NE) {
            int d = dst[i];
            bk[j] = d >> 7;
            pk[j] = src[i] * BKT + (d & (BKT - 1));
            of[j] = atomicAdd(&lcnt[bk[j]], 1);
        } else bk[j] = -1;
    }
    __syncthreads();
    for (int b = t; b < NBK; b += 512) {
        int c = lcnt[b];
        if (c) lbase[b] = atomicAdd(&gcur[b], c);
    }
    __syncthreads();
#pragma unroll
    for (int j = 0; j < 8; ++j)
        if (bk[j] >= 0) ebuf[lbase[bk[j]] + of[j]] = pk[j];
}

// out[n][j] = dinv[n] * sum_k in[n][k] * W[k][j]   (16 rows/block, 1024 thr)
__global__ void k_mm_scale(const float* __restrict__ in, const float* __restrict__ W,
                           const float* __restrict__ dinv, float* __restrict__ out) {
    __shared__ float Ws[D * D];       // 16 KB
    __shared__ float rows[16][D];
    int t = threadIdx.x;              // 1024 threads: 16 rows x 64 cols
    for (int i = t; i < D * D; i += 1024) Ws[i] = W[i];
    int r = t >> 6, j = t & 63;
    int n = blockIdx.x * 16 + r;      // NN % 16 == 0
    rows[r][j] = in[(long)n * D + j];
    __syncthreads();
    float acc = 0.f;
#pragma unroll
    for (int k = 0; k < D; ++k) acc += rows[r][k] * Ws[k * D + j];
    out[(long)n * D + j] = acc * dinv[n];
}

// per-bucket aggregation into a 32 KB LDS accumulator, epilogue fused.
// LAYER=1: h = relu(..) -> out.  LAYER=2: pooled partial sums -> psum.
template <int LAYER>
__global__ __launch_bounds__(512) void
k_agg(const int* __restrict__ boffs, const int* __restrict__ ebuf,
      const float* __restrict__ g, const float* __restrict__ dinv,
      const float* __restrict__ bias, const int* __restrict__ batch,
      float* __restrict__ out, float* __restrict__ psum) {
    __shared__ float acc[BKT * D];    // 32 KB
    int t = threadIdx.x;
    int lane = t & 63;
    int w = __builtin_amdgcn_readfirstlane(t >> 6);   // wave 0..7
    int b = blockIdx.x;
    int v0 = b * BKT;
    for (int i = t; i < BKT * D; i += 512) acc[i] = 0.f;
    __syncthreads();
    int gBeg = boffs[b], gEnd = boffs[b + 1];
    for (int e = gBeg + w * 4; e < gEnd; e += 32) {   // 4 edges/wave-iter, 8 waves
        if (e + 4 <= gEnd) {
            int p0 = ebuf[e], p1 = ebuf[e + 1], p2 = ebuf[e + 2], p3 = ebuf[e + 3];
            float a0 = g[(long)(p0 >> 7) * D + lane];
            float a1 = g[(long)(p1 >> 7) * D + lane];
            float a2 = g[(long)(p2 >> 7) * D + lane];
            float a3 = g[(long)(p3 >> 7) * D + lane];
            atomicAdd(&acc[(p0 & 127) * D + lane], a0);
            atomicAdd(&acc[(p1 & 127) * D + lane], a1);
            atomicAdd(&acc[(p2 & 127) * D + lane], a2);
            atomicAdd(&acc[(p3 & 127) * D + lane], a3);
        } else {
            for (int k = e; k < gEnd; ++k) {
                int p = ebuf[k];
                atomicAdd(&acc[(p & 127) * D + lane], g[(long)(p >> 7) * D + lane]);
            }
        }
    }
    __syncthreads();
    // epilogue: wave w handles 16 consecutive nodes
    float bl = bias[lane];
    float pacc = 0.f;
    int pg = -1;
    for (int i = 0; i < 16; ++i) {
        int v = v0 + w * 16 + i;
        if (v >= NN) break;
        float val = (acc[(w * 16 + i) * D + lane] + g[(long)v * D + lane]) * dinv[v] + bl;
        if (LAYER == 1) {
            out[(long)v * D + lane] = fmaxf(val, 0.f);
        } else {
            int bg = batch[v];
            if (bg != pg) {
                if (pg >= 0) atomicAdd(&psum[pg * D + lane], pacc);
                pacc = 0.f;
                pg = bg;
            }
            pacc += val;
        }
    }
    if (LAYER == 2 && pg >= 0) atomicAdd(&psum[pg * D + lane], pacc);
}

// per-graph head: mean, 64->32 relu, 32->8
__global__ void k_head(const float* __restrict__ psum, const int* __restrict__ cnt,
                       const float* __restrict__ lw1, const float* __restrict__ lb1,
                       const float* __restrict__ lw2, const float* __restrict__ lb2,
                       float* __restrict__ out) {
    __shared__ float pl[D];
    __shared__ float z[DH];
    int g = blockIdx.x;
    int t = threadIdx.x;  // 64
    float c = fmaxf((float)cnt[g], 1.0f);
    pl[t] = psum[(long)g * D + t] / c;
    __syncthreads();
    if (t < DH) {
        float a = lb1[t];
#pragma unroll
        for (int k = 0; k < D; ++k) a += pl[k] * lw1[k * DH + t];
        z[t] = fmaxf(a, 0.f);
    }
    __syncthreads();
    if (t < DO) {
        float a = lb2[t];
#pragma unroll
        for (int j = 0; j < DH; ++j) a += z[j] * lw2[j * DO + t];
        out[g * DO + t] = a;
    }
}

extern "C" void kernel_launch(void* const* d_in, const int* in_sizes, int n_in,
                              void* d_out, int out_size, void* d_ws, size_t ws_size,
                              hipStream_t stream) {
    const float* x    = (const float*)d_in[0];
    const int*   ei   = (const int*)  d_in[1];
    const int*   batch= (const int*)  d_in[2];
    const float* W1   = (const float*)d_in[3];
    const float* b1   = (const float*)d_in[4];
    const float* W2   = (const float*)d_in[5];
    const float* b2   = (const float*)d_in[6];
    const float* lw1  = (const float*)d_in[7];
    const float* lb1  = (const float*)d_in[8];
    const float* lw2  = (const float*)d_in[9];
    const float* lb2  = (const float*)d_in[10];
    float* out = (float*)d_out;

    const int* srcv = ei;        // edge_index[0]
    const int* dstv = ei + NE;   // edge_index[1]

    char* ws = (char*)d_ws;
    size_t off = 0;
    auto alloc = [&](size_t bytes) {
        void* p = ws + off;
        off = (off + bytes + 255) & ~(size_t)255;
        return p;
    };
    int*   deg   = (int*)  alloc((size_t)NN * 4);
    int*   cnt   = (int*)  alloc((size_t)NG * 4);
    int*   bsum  = (int*)  alloc((size_t)NBK * 4);
    int*   boffs = (int*)  alloc((size_t)(NBK + 1) * 4);
    int*   gcur  = (int*)  alloc((size_t)NBK * 4);
    int*   ebuf  = (int*)  alloc((size_t)NE * 4);       // 6.4 MB
    float* dinv  = (float*)alloc((size_t)NN * 4);
    float* psum  = (float*)alloc((size_t)NG * D * 4);
    float* bufA  = (float*)alloc((size_t)NN * D * 4);   // 25.6 MB
    float* bufB  = (float*)alloc((size_t)NN * D * 4);   // 25.6 MB

    hipMemsetAsync(deg,  0, (size_t)NN * 4,     stream);
    hipMemsetAsync(cnt,  0, (size_t)NG * 4,     stream);
    hipMemsetAsync(psum, 0, (size_t)NG * D * 4, stream);

    k_count2    <<<(NE + 255) / 256, 256, 0, stream>>>(dstv, batch, deg, cnt);
    k_bucket_sum<<<NBK, BKT, 0, stream>>>(deg, bsum);
    k_scan      <<<1, 1024, 0, stream>>>(bsum, boffs, gcur);
    k_dinv      <<<(NN + 255) / 256, 256, 0, stream>>>(deg, dinv);
    k_bin       <<<NCH, 512, 0, stream>>>(srcv, dstv, gcur, ebuf);

    // layer 1: g1 = (x @ W1) * dinv -> bufA ; h1 = relu(agg) -> bufB
    k_mm_scale<<<NN / 16, 1024, 0, stream>>>(x, W1, dinv, bufA);
    k_agg<1><<<NBK, 512, 0, stream>>>(boffs, ebuf, bufA, dinv, b1, batch, bufB, nullptr);

    // layer 2: g2 = (h1 @ W2) * dinv -> bufA ; agg + pool -> psum
    k_mm_scale<<<NN / 16, 1024, 0, stream>>>(bufB, W2, dinv, bufA);
    k_agg<2><<<NBK, 512, 0, stream>>>(boffs, ebuf, bufA, dinv, b2, batch, nullptr, psum);

    k_head<<<NG, 64, 0, stream>>>(psum, cnt, lw1, lb1, lw2, lb2, out);
}

// Round 5
// 484.194 us; speedup vs baseline: 3.4872x; 3.4872x over previous
//
#include <hip/hip_runtime.h>

static constexpr int NN  = 100000;   // nodes
static constexpr int NE  = 1600000;  // edges
static constexpr int NG  = 1000;     // graphs
static constexpr int D   = 64;       // D_IN = D_HID
static constexpr int DH  = 32;       // head hidden
static constexpr int DO  = 8;        // out dim
static constexpr int NB  = 391;      // ceil(NN/256) scan blocks
static constexpr int BKT = 128;      // nodes per bucket (7 bits)
static constexpr int NBK = (NN + BKT - 1) / BKT;     // 782
static constexpr int CHUNK = 4096;                   // edges per binning block
static constexpr int NCH = (NE + CHUNK - 1) / CHUNK; // 391
static constexpr int NPW = 8;        // node-groups (of 4) per wave in k_agg

// deg[dst[i]]++ and cnt[batch[i]]++ in one pass
__global__ void k_count2(const int* __restrict__ dst, const int* __restrict__ batch,
                         int* __restrict__ deg, int* __restrict__ cnt) {
    int i = blockIdx.x * 256 + threadIdx.x;
    if (i < NE) atomicAdd(&deg[dst[i]], 1);
    if (i < NN) atomicAdd(&cnt[batch[i]], 1);
}

// per-block sums of deg for the prefix scan
__global__ void k_blocksum(const int* __restrict__ deg, int* __restrict__ bsum) {
    __shared__ int ws[4];
    int i = blockIdx.x * 256 + threadIdx.x;
    int v = (i < NN) ? deg[i] : 0;
    for (int o = 32; o; o >>= 1) v += __shfl_down(v, o);
    if ((threadIdx.x & 63) == 0) ws[threadIdx.x >> 6] = v;
    __syncthreads();
    if (threadIdx.x == 0) bsum[blockIdx.x] = ws[0] + ws[1] + ws[2] + ws[3];
}

// single-block exclusive scan of the NB block sums
__global__ void k_scan_bsum(const int* __restrict__ bsum, int* __restrict__ boffs) {
    __shared__ int s[512];
    int t = threadIdx.x;
    int v = (t < NB) ? bsum[t] : 0;
    s[t] = v;
    __syncthreads();
    for (int o = 1; o < 512; o <<= 1) {
        int a = (t >= o) ? s[t - o] : 0;
        __syncthreads();
        s[t] += a;
        __syncthreads();
    }
    if (t < NB) boffs[t] = s[t] - v;   // exclusive
}

// rowptr + dinv + per-bucket cursor seed (gcur[b] = rowptr[b*128])
__global__ void k_write_ptr(const int* __restrict__ deg, const int* __restrict__ boffs,
                            int* __restrict__ rowptr, int* __restrict__ gcur,
                            float* __restrict__ dinv) {
    __shared__ int s[256];
    int t = threadIdx.x, i = blockIdx.x * 256 + t;
    int d = (i < NN) ? deg[i] : 0;
    s[t] = d;
    __syncthreads();
    for (int o = 1; o < 256; o <<= 1) {
        int a = (t >= o) ? s[t - o] : 0;
        __syncthreads();
        s[t] += a;
        __syncthreads();
    }
    if (i < NN) {
        int excl = s[t] - d + boffs[blockIdx.x];
        rowptr[i] = excl;
        dinv[i]   = rsqrtf((float)(d + 1));
        if ((i & (BKT - 1)) == 0) gcur[i >> 7] = excl;
    }
    if (i == 0) rowptr[NN] = NE;
}

// two-phase binning: LDS histogram -> per-bucket range reservation -> scatter
// packed edge = src*128 + (dst & 127), grouped by bucket dst>>7
__global__ __launch_bounds__(512) void
k_bin(const int* __restrict__ src, const int* __restrict__ dst,
      int* __restrict__ gcur, int* __restrict__ ebuf) {
    __shared__ int lcnt[NBK];
    __shared__ int lbase[NBK];
    int t = threadIdx.x;
    long base = (long)blockIdx.x * CHUNK;
    for (int b = t; b < NBK; b += 512) lcnt[b] = 0;
    __syncthreads();
    int pk[8], bk[8], of[8];
#pragma unroll
    for (int j = 0; j < 8; ++j) {
        long i = base + j * 512 + t;
        if (i < NE) {
            int d = dst[i];
            bk[j] = d >> 7;
            pk[j] = src[i] * BKT + (d & (BKT - 1));
            of[j] = atomicAdd(&lcnt[bk[j]], 1);
        } else bk[j] = -1;
    }
    __syncthreads();
    for (int b = t; b < NBK; b += 512) {
        int c = lcnt[b];
        if (c) lbase[b] = atomicAdd(&gcur[b], c);
    }
    __syncthreads();
#pragma unroll
    for (int j = 0; j < 8; ++j)
        if (bk[j] >= 0) ebuf[lbase[bk[j]] + of[j]] = pk[j];
}

// per-bucket exact CSR placement: LDS int cursors seeded from rowptr;
// writes stay inside the bucket's contiguous ~8 KB slice of csr.
__global__ __launch_bounds__(256) void
k_csr(const int* __restrict__ rowptr, const int* __restrict__ ebuf,
      int* __restrict__ csr) {
    __shared__ int lcur[BKT];
    int b = blockIdx.x, t = threadIdx.x;
    int v0 = b * BKT;
    if (t < BKT) {
        int v = v0 + t;
        lcur[t] = (v < NN) ? rowptr[v] : 0;
    }
    __syncthreads();
    int beg = rowptr[v0];
    int end = rowptr[min(v0 + BKT, NN)];
    for (int e = beg + t; e < end; e += 256) {
        int p = ebuf[e];
        int slot = atomicAdd(&lcur[p & (BKT - 1)], 1);
        csr[slot] = p >> 7;
    }
}

// out[n][j] = dinv[n] * sum_k in[n][k] * W[k][j]   (16 rows/block, 1024 thr)
__global__ void k_mm_scale(const float* __restrict__ in, const float* __restrict__ W,
                           const float* __restrict__ dinv, float* __restrict__ out) {
    __shared__ float Ws[D * D];       // 16 KB
    __shared__ float rows[16][D];
    int t = threadIdx.x;              // 1024 threads: 16 rows x 64 cols
    for (int i = t; i < D * D; i += 1024) Ws[i] = W[i];
    int r = t >> 6, j = t & 63;
    int n = blockIdx.x * 16 + r;      // NN % 16 == 0
    rows[r][j] = in[(long)n * D + j];
    __syncthreads();
    float acc = 0.f;
#pragma unroll
    for (int k = 0; k < D; ++k) acc += rows[r][k] * Ws[k * D + j];
    out[(long)n * D + j] = acc * dinv[n];
}

// CSR pull aggregation, float4 gathers, 4 nodes per wave per step.
// lane = slot(2b) x feature-group(4b); one gather instr covers 4 edges (1 KB).
// LAYER=1: h = relu(..) -> out4.  LAYER=2: pooled partial sums -> psum.
template <int LAYER>
__global__ __launch_bounds__(256) void
k_agg(const int* __restrict__ rowptr, const int* __restrict__ csr,
      const float4* __restrict__ g4, const float* __restrict__ dinv,
      const float* __restrict__ bias, const int* __restrict__ batch,
      float4* __restrict__ out4, float* __restrict__ psum) {
    int t = threadIdx.x;
    int lane = t & 63;
    int fg = lane & 15;          // float4 feature group: dims fg*4 .. fg*4+3
    int slot = lane >> 4;        // 0..3, node offset within the group of 4
    int wid = blockIdx.x * 4 + (t >> 6);
    int vstart = wid * (4 * NPW);
    if (vstart >= NN) return;
    float4 b4 = ((const float4*)bias)[fg];
    float4 pacc = make_float4(0.f, 0.f, 0.f, 0.f);
    int pg = -1;
    for (int i = 0; i < NPW; ++i) {
        int v = vstart + i * 4 + slot;
        int vc = min(v, NN - 1);
        int beg = rowptr[vc];
        int len = rowptr[vc + 1] - beg;
        if (v >= NN) len = 0;
        int lmax = len;
        lmax = max(lmax, __shfl_xor(lmax, 16));
        lmax = max(lmax, __shfl_xor(lmax, 32));
        float4 s4 = g4[(long)vc * 16 + fg];   // self-loop term
        for (int e = 0; e < lmax; e += 4) {
#pragma unroll
            for (int j = 0; j < 4; ++j) {
                int ee = e + j;
                float m = (ee < len) ? 1.f : 0.f;
                int idx = beg + ((ee < len) ? ee : 0);
                idx = min(idx, NE - 1);
                int srcn = csr[idx];
                float4 a = g4[(long)srcn * 16 + fg];
                s4.x += m * a.x; s4.y += m * a.y;
                s4.z += m * a.z; s4.w += m * a.w;
            }
        }
        float dv = dinv[vc];
        float4 val = make_float4(s4.x * dv + b4.x, s4.y * dv + b4.y,
                                 s4.z * dv + b4.z, s4.w * dv + b4.w);
        if (LAYER == 1) {
            if (v < NN) {
                val.x = fmaxf(val.x, 0.f); val.y = fmaxf(val.y, 0.f);
                val.z = fmaxf(val.z, 0.f); val.w = fmaxf(val.w, 0.f);
                out4[(long)v * 16 + fg] = val;
            }
        } else {
            if (v < NN) {
                int bg = batch[v];
                if (bg != pg) {
                    if (pg >= 0) {
                        atomicAdd(&psum[pg * D + fg * 4 + 0], pacc.x);
                        atomicAdd(&psum[pg * D + fg * 4 + 1], pacc.y);
                        atomicAdd(&psum[pg * D + fg * 4 + 2], pacc.z);
                        atomicAdd(&psum[pg * D + fg * 4 + 3], pacc.w);
                    }
                    pacc = make_float4(0.f, 0.f, 0.f, 0.f);
                    pg = bg;
                }
                pacc.x += val.x; pacc.y += val.y;
                pacc.z += val.z; pacc.w += val.w;
            }
        }
    }
    if (LAYER == 2 && pg >= 0) {
        atomicAdd(&psum[pg * D + fg * 4 + 0], pacc.x);
        atomicAdd(&psum[pg * D + fg * 4 + 1], pacc.y);
        atomicAdd(&psum[pg * D + fg * 4 + 2], pacc.z);
        atomicAdd(&psum[pg * D + fg * 4 + 3], pacc.w);
    }
}

// per-graph head: mean, 64->32 relu, 32->8
__global__ void k_head(const float* __restrict__ psum, const int* __restrict__ cnt,
                       const float* __restrict__ lw1, const float* __restrict__ lb1,
                       const float* __restrict__ lw2, const float* __restrict__ lb2,
                       float* __restrict__ out) {
    __shared__ float pl[D];
    __shared__ float z[DH];
    int g = blockIdx.x;
    int t = threadIdx.x;  // 64
    float c = fmaxf((float)cnt[g], 1.0f);
    pl[t] = psum[(long)g * D + t] / c;
    __syncthreads();
    if (t < DH) {
        float a = lb1[t];
#pragma unroll
        for (int k = 0; k < D; ++k) a += pl[k] * lw1[k * DH + t];
        z[t] = fmaxf(a, 0.f);
    }
    __syncthreads();
    if (t < DO) {
        float a = lb2[t];
#pragma unroll
        for (int j = 0; j < DH; ++j) a += z[j] * lw2[j * DO + t];
        out[g * DO + t] = a;
    }
}

extern "C" void kernel_launch(void* const* d_in, const int* in_sizes, int n_in,
                              void* d_out, int out_size, void* d_ws, size_t ws_size,
                              hipStream_t stream) {
    const float* x    = (const float*)d_in[0];
    const int*   ei   = (const int*)  d_in[1];
    const int*   batch= (const int*)  d_in[2];
    const float* W1   = (const float*)d_in[3];
    const float* b1   = (const float*)d_in[4];
    const float* W2   = (const float*)d_in[5];
    const float* b2   = (const float*)d_in[6];
    const float* lw1  = (const float*)d_in[7];
    const float* lb1  = (const float*)d_in[8];
    const float* lw2  = (const float*)d_in[9];
    const float* lb2  = (const float*)d_in[10];
    float* out = (float*)d_out;

    const int* srcv = ei;        // edge_index[0]
    const int* dstv = ei + NE;   // edge_index[1]

    char* ws = (char*)d_ws;
    size_t off = 0;
    auto alloc = [&](size_t bytes) {
        void* p = ws + off;
        off = (off + bytes + 255) & ~(size_t)255;
        return p;
    };
    int*   deg    = (int*)  alloc((size_t)NN * 4);
    int*   cnt    = (int*)  alloc((size_t)NG * 4);
    int*   bsum   = (int*)  alloc((size_t)NB * 4);
    int*   boffs  = (int*)  alloc((size_t)NB * 4);
    int*   rowptr = (int*)  alloc((size_t)(NN + 1) * 4);
    int*   gcur   = (int*)  alloc((size_t)NBK * 4);
    int*   csr    = (int*)  alloc((size_t)NE * 4);      // 6.4 MB
    float* dinv   = (float*)alloc((size_t)NN * 4);
    float* psum   = (float*)alloc((size_t)NG * D * 4);
    float* bufA   = (float*)alloc((size_t)NN * D * 4);  // 25.6 MB
    float* bufB   = (float*)alloc((size_t)NN * D * 4);  // 25.6 MB
    int*   ebuf   = (int*)bufA;  // binning scratch; dead before bufA first written

    hipMemsetAsync(deg,  0, (size_t)NN * 4,     stream);
    hipMemsetAsync(cnt,  0, (size_t)NG * 4,     stream);
    hipMemsetAsync(psum, 0, (size_t)NG * D * 4, stream);

    k_count2   <<<(NE + 255) / 256, 256, 0, stream>>>(dstv, batch, deg, cnt);
    k_blocksum <<<NB, 256, 0, stream>>>(deg, bsum);
    k_scan_bsum<<<1, 512, 0, stream>>>(bsum, boffs);
    k_write_ptr<<<NB, 256, 0, stream>>>(deg, boffs, rowptr, gcur, dinv);
    k_bin      <<<NCH, 512, 0, stream>>>(srcv, dstv, gcur, ebuf);
    k_csr      <<<NBK, 256, 0, stream>>>(rowptr, ebuf, csr);

    // layer 1: g1 = (x @ W1) * dinv -> bufA ; h1 = relu(agg) -> bufB
    k_mm_scale<<<NN / 16, 1024, 0, stream>>>(x, W1, dinv, bufA);
    k_agg<1><<<(NN + 16 * NPW - 1) / (16 * NPW), 256, 0, stream>>>(
        rowptr, csr, (const float4*)bufA, dinv, b1, batch, (float4*)bufB, nullptr);

    // layer 2: g2 = (h1 @ W2) * dinv -> bufA ; agg + pool -> psum
    k_mm_scale<<<NN / 16, 1024, 0, stream>>>(bufB, W2, dinv, bufA);
    k_agg<2><<<(NN + 16 * NPW - 1) / (16 * NPW), 256, 0, stream>>>(
        rowptr, csr, (const float4*)bufA, dinv, b2, batch, nullptr, psum);

    k_head<<<NG, 64, 0, stream>>>(psum, cnt, lw1, lb1, lw2, lb2, out);
}

// Round 6
// 392.531 us; speedup vs baseline: 4.3015x; 1.2335x over previous
//
#include <hip/hip_runtime.h>

static constexpr int NN  = 100000;   // nodes
static constexpr int NE  = 1600000;  // edges
static constexpr int NG  = 1000;     // graphs
static constexpr int D   = 64;       // D_IN = D_HID
static constexpr int DH  = 32;       // head hidden
static constexpr int DO  = 8;        // out dim
static constexpr int BKT = 128;      // nodes per bucket (7 bits)
static constexpr int NBK = (NN + BKT - 1) / BKT;     // 782
static constexpr int CHUNK = 4096;                   // edges per chunk block
static constexpr int NCH = (NE + CHUNK - 1) / CHUNK; // 391
static constexpr int NPW = 8;        // node-groups (of 4) per wave in k_agg

// per-chunk LDS histogram of dst buckets -> count matrix (plain stores, no global atomics)
__global__ __launch_bounds__(512) void
k_hist(const int* __restrict__ dst, int* __restrict__ cntmat) {
    __shared__ int lcnt[NBK];
    int t = threadIdx.x;
    long base = (long)blockIdx.x * CHUNK;
    for (int b = t; b < NBK; b += 512) lcnt[b] = 0;
    __syncthreads();
#pragma unroll
    for (int j = 0; j < 8; ++j) {
        long i = base + j * 512 + t;
        if (i < NE) atomicAdd(&lcnt[dst[i] >> 7], 1);   // LDS int atomic
    }
    __syncthreads();
    for (int b = t; b < NBK; b += 512)
        cntmat[blockIdx.x * NBK + b] = lcnt[b];
}

// bucket totals = column sums of cntmat
__global__ void k_colsum(const int* __restrict__ cntmat, int* __restrict__ bsum) {
    int b = blockIdx.x;   // bucket
    int t = threadIdx.x;  // 64
    int s = 0;
    for (int c = t; c < NCH; c += 64) s += cntmat[c * NBK + b];
    for (int o = 32; o; o >>= 1) s += __shfl_down(s, o);
    if (t == 0) bsum[b] = s;
}

// single-block exclusive scan of NBK bucket totals -> boffs (+NE sentinel)
__global__ void k_scan(const int* __restrict__ bsum, int* __restrict__ boffs) {
    __shared__ int s[1024];
    int t = threadIdx.x;
    int v = (t < NBK) ? bsum[t] : 0;
    s[t] = v;
    __syncthreads();
    for (int o = 1; o < 1024; o <<= 1) {
        int a = (t >= o) ? s[t - o] : 0;
        __syncthreads();
        s[t] += a;
        __syncthreads();
    }
    if (t < NBK) boffs[t] = s[t] - v;
    if (t == 0) boffs[NBK] = NE;
}

// per-bucket scan across chunks: cntmat becomes exact write base per (chunk,bucket)
__global__ __launch_bounds__(512) void
k_rowscan(int* __restrict__ cntmat, const int* __restrict__ boffs) {
    __shared__ int s[512];
    int b = blockIdx.x, t = threadIdx.x;
    int v = (t < NCH) ? cntmat[t * NBK + b] : 0;
    s[t] = v;
    __syncthreads();
    for (int o = 1; o < 512; o <<= 1) {
        int a = (t >= o) ? s[t - o] : 0;
        __syncthreads();
        s[t] += a;
        __syncthreads();
    }
    if (t < NCH) cntmat[t * NBK + b] = boffs[b] + s[t] - v;
}

// binning with precomputed bases: zero global atomics.
// packed edge = src*128 + (dst & 127), grouped by bucket dst>>7
__global__ __launch_bounds__(512) void
k_bin(const int* __restrict__ src, const int* __restrict__ dst,
      const int* __restrict__ cntmat, int* __restrict__ ebuf) {
    __shared__ int lcnt[NBK];
    __shared__ int lbase[NBK];
    int t = threadIdx.x;
    long base = (long)blockIdx.x * CHUNK;
    for (int b = t; b < NBK; b += 512) lcnt[b] = 0;
    __syncthreads();
    int pk[8], bk[8], of[8];
#pragma unroll
    for (int j = 0; j < 8; ++j) {
        long i = base + j * 512 + t;
        if (i < NE) {
            int d = dst[i];
            bk[j] = d >> 7;
            pk[j] = src[i] * BKT + (d & (BKT - 1));
            of[j] = atomicAdd(&lcnt[bk[j]], 1);
        } else bk[j] = -1;
    }
    __syncthreads();
    for (int b = t; b < NBK; b += 512) lbase[b] = cntmat[blockIdx.x * NBK + b];
    __syncthreads();
#pragma unroll
    for (int j = 0; j < 8; ++j)
        if (bk[j] >= 0) ebuf[lbase[bk[j]] + of[j]] = pk[j];
}

// per-bucket: LDS histogram of local idx -> deg -> rowptr/dinv (plain stores),
// then exact CSR scatter with LDS cursors. Replaces the whole deg/scan chain.
__global__ __launch_bounds__(256) void
k_csrdeg(const int* __restrict__ boffs, const int* __restrict__ ebuf,
         int* __restrict__ rowptr, float* __restrict__ dinv, int* __restrict__ csr) {
    __shared__ int hist[BKT];
    __shared__ int sc[BKT];
    __shared__ int lcur[BKT];
    int b = blockIdx.x, t = threadIdx.x;
    if (t < BKT) hist[t] = 0;
    __syncthreads();
    int beg = boffs[b], end = boffs[b + 1];
    for (int e = beg + t; e < end; e += 256)
        atomicAdd(&hist[ebuf[e] & (BKT - 1)], 1);
    __syncthreads();
    if (t < BKT) sc[t] = hist[t];
    __syncthreads();
    for (int o = 1; o < BKT; o <<= 1) {
        int a = (t < BKT && t >= o) ? sc[t - o] : 0;
        __syncthreads();
        if (t < BKT) sc[t] += a;
        __syncthreads();
    }
    int v0 = b * BKT;
    if (t < BKT) {
        int v = v0 + t;
        if (v < NN) {
            int excl = beg + sc[t] - hist[t];
            rowptr[v] = excl;
            dinv[v]   = rsqrtf((float)(hist[t] + 1));
            lcur[t]   = excl;
        }
    }
    if (b == NBK - 1 && t == 0) rowptr[NN] = NE;
    __syncthreads();
    for (int e = beg + t; e < end; e += 256) {
        int p = ebuf[e];
        int slot = atomicAdd(&lcur[p & (BKT - 1)], 1);
        csr[slot] = p >> 7;
    }
}

// out[n][j] = dinv[n] * sum_k in[n][k] * W[k][j]   (16 rows/block, 1024 thr)
__global__ void k_mm_scale(const float* __restrict__ in, const float* __restrict__ W,
                           const float* __restrict__ dinv, float* __restrict__ out) {
    __shared__ float Ws[D * D];       // 16 KB
    __shared__ float rows[16][D];
    int t = threadIdx.x;              // 1024 threads: 16 rows x 64 cols
    for (int i = t; i < D * D; i += 1024) Ws[i] = W[i];
    int r = t >> 6, j = t & 63;
    int n = blockIdx.x * 16 + r;      // NN % 16 == 0
    rows[r][j] = in[(long)n * D + j];
    __syncthreads();
    float acc = 0.f;
#pragma unroll
    for (int k = 0; k < D; ++k) acc += rows[r][k] * Ws[k * D + j];
    out[(long)n * D + j] = acc * dinv[n];
}

// CSR pull aggregation, float4 gathers, 4 nodes per wave per step.
// LAYER=1: h = relu(..) -> out4.  LAYER=2: pooled partial sums -> psum.
template <int LAYER>
__global__ __launch_bounds__(256) void
k_agg(const int* __restrict__ rowptr, const int* __restrict__ csr,
      const float4* __restrict__ g4, const float* __restrict__ dinv,
      const float* __restrict__ bias, const int* __restrict__ batch,
      float4* __restrict__ out4, float* __restrict__ psum) {
    int t = threadIdx.x;
    int lane = t & 63;
    int fg = lane & 15;          // float4 feature group
    int slot = lane >> 4;        // 0..3, node offset within group of 4
    int wid = blockIdx.x * 4 + (t >> 6);
    int vstart = wid * (4 * NPW);
    if (vstart >= NN) return;
    float4 b4 = ((const float4*)bias)[fg];
    float4 pacc = make_float4(0.f, 0.f, 0.f, 0.f);
    int pg = -1;
    for (int i = 0; i < NPW; ++i) {
        int v = vstart + i * 4 + slot;
        int vc = min(v, NN - 1);
        int beg = rowptr[vc];
        int len = rowptr[vc + 1] - beg;
        if (v >= NN) len = 0;
        int lmax = len;
        lmax = max(lmax, __shfl_xor(lmax, 16));
        lmax = max(lmax, __shfl_xor(lmax, 32));
        float4 s4 = g4[(long)vc * 16 + fg];   // self-loop term
        for (int e = 0; e < lmax; e += 4) {
#pragma unroll
            for (int j = 0; j < 4; ++j) {
                int ee = e + j;
                float m = (ee < len) ? 1.f : 0.f;
                int idx = beg + ((ee < len) ? ee : 0);
                idx = min(idx, NE - 1);
                int srcn = csr[idx];
                float4 a = g4[(long)srcn * 16 + fg];
                s4.x += m * a.x; s4.y += m * a.y;
                s4.z += m * a.z; s4.w += m * a.w;
            }
        }
        float dv = dinv[vc];
        float4 val = make_float4(s4.x * dv + b4.x, s4.y * dv + b4.y,
                                 s4.z * dv + b4.z, s4.w * dv + b4.w);
        if (LAYER == 1) {
            if (v < NN) {
                val.x = fmaxf(val.x, 0.f); val.y = fmaxf(val.y, 0.f);
                val.z = fmaxf(val.z, 0.f); val.w = fmaxf(val.w, 0.f);
                out4[(long)v * 16 + fg] = val;
            }
        } else {
            if (v < NN) {
                int bg = batch[v];
                if (bg != pg) {
                    if (pg >= 0) {
                        atomicAdd(&psum[pg * D + fg * 4 + 0], pacc.x);
                        atomicAdd(&psum[pg * D + fg * 4 + 1], pacc.y);
                        atomicAdd(&psum[pg * D + fg * 4 + 2], pacc.z);
                        atomicAdd(&psum[pg * D + fg * 4 + 3], pacc.w);
                    }
                    pacc = make_float4(0.f, 0.f, 0.f, 0.f);
                    pg = bg;
                }
                pacc.x += val.x; pacc.y += val.y;
                pacc.z += val.z; pacc.w += val.w;
            }
        }
    }
    if (LAYER == 2 && pg >= 0) {
        atomicAdd(&psum[pg * D + fg * 4 + 0], pacc.x);
        atomicAdd(&psum[pg * D + fg * 4 + 1], pacc.y);
        atomicAdd(&psum[pg * D + fg * 4 + 2], pacc.z);
        atomicAdd(&psum[pg * D + fg * 4 + 3], pacc.w);
    }
}

// per-graph head: counts via binary search on sorted batch; mean, 64->32 relu, 32->8
__global__ void k_head(const float* __restrict__ psum, const int* __restrict__ batch,
                       const float* __restrict__ lw1, const float* __restrict__ lb1,
                       const float* __restrict__ lw2, const float* __restrict__ lb2,
                       float* __restrict__ out) {
    __shared__ float pl[D];
    __shared__ float z[DH];
    int g = blockIdx.x;
    int t = threadIdx.x;  // 64
    int lo = 0, hi = NN;
    while (lo < hi) { int m = (lo + hi) >> 1; if (batch[m] < g) lo = m + 1; else hi = m; }
    int lb = lo;
    hi = NN;
    while (lo < hi) { int m = (lo + hi) >> 1; if (batch[m] < g + 1) lo = m + 1; else hi = m; }
    float c = fmaxf((float)(lo - lb), 1.0f);
    pl[t] = psum[(long)g * D + t] / c;
    __syncthreads();
    if (t < DH) {
        float a = lb1[t];
#pragma unroll
        for (int k = 0; k < D; ++k) a += pl[k] * lw1[k * DH + t];
        z[t] = fmaxf(a, 0.f);
    }
    __syncthreads();
    if (t < DO) {
        float a = lb2[t];
#pragma unroll
        for (int j = 0; j < DH; ++j) a += z[j] * lw2[j * DO + t];
        out[g * DO + t] = a;
    }
}

extern "C" void kernel_launch(void* const* d_in, const int* in_sizes, int n_in,
                              void* d_out, int out_size, void* d_ws, size_t ws_size,
                              hipStream_t stream) {
    const float* x    = (const float*)d_in[0];
    const int*   ei   = (const int*)  d_in[1];
    const int*   batch= (const int*)  d_in[2];
    const float* W1   = (const float*)d_in[3];
    const float* b1   = (const float*)d_in[4];
    const float* W2   = (const float*)d_in[5];
    const float* b2   = (const float*)d_in[6];
    const float* lw1  = (const float*)d_in[7];
    const float* lb1  = (const float*)d_in[8];
    const float* lw2  = (const float*)d_in[9];
    const float* lb2  = (const float*)d_in[10];
    float* out = (float*)d_out;

    const int* srcv = ei;        // edge_index[0]
    const int* dstv = ei + NE;   // edge_index[1]

    char* ws = (char*)d_ws;
    size_t off = 0;
    auto alloc = [&](size_t bytes) {
        void* p = ws + off;
        off = (off + bytes + 255) & ~(size_t)255;
        return p;
    };
    int*   cntmat = (int*)  alloc((size_t)NCH * NBK * 4);  // 1.22 MB
    int*   bsum   = (int*)  alloc((size_t)NBK * 4);
    int*   boffs  = (int*)  alloc((size_t)(NBK + 1) * 4);
    int*   rowptr = (int*)  alloc((size_t)(NN + 1) * 4);
    int*   csr    = (int*)  alloc((size_t)NE * 4);         // 6.4 MB
    float* dinv   = (float*)alloc((size_t)NN * 4);
    float* psum   = (float*)alloc((size_t)NG * D * 4);
    float* bufA   = (float*)alloc((size_t)NN * D * 4);     // 25.6 MB
    float* bufB   = (float*)alloc((size_t)NN * D * 4);     // 25.6 MB
    int*   ebuf   = (int*)bufA;  // binning scratch; dead before bufA first written

    hipMemsetAsync(psum, 0, (size_t)NG * D * 4, stream);

    k_hist   <<<NCH, 512, 0, stream>>>(dstv, cntmat);
    k_colsum <<<NBK, 64, 0, stream>>>(cntmat, bsum);
    k_scan   <<<1, 1024, 0, stream>>>(bsum, boffs);
    k_rowscan<<<NBK, 512, 0, stream>>>(cntmat, boffs);
    k_bin    <<<NCH, 512, 0, stream>>>(srcv, dstv, cntmat, ebuf);
    k_csrdeg <<<NBK, 256, 0, stream>>>(boffs, ebuf, rowptr, dinv, csr);

    // layer 1: g1 = (x @ W1) * dinv -> bufA ; h1 = relu(agg) -> bufB
    k_mm_scale<<<NN / 16, 1024, 0, stream>>>(x, W1, dinv, bufA);
    k_agg<1><<<(NN + 16 * NPW - 1) / (16 * NPW), 256, 0, stream>>>(
        rowptr, csr, (const float4*)bufA, dinv, b1, batch, (float4*)bufB, nullptr);

    // layer 2: g2 = (h1 @ W2) * dinv -> bufA ; agg + pool -> psum
    k_mm_scale<<<NN / 16, 1024, 0, stream>>>(bufB, W2, dinv, bufA);
    k_agg<2><<<(NN + 16 * NPW - 1) / (16 * NPW), 256, 0, stream>>>(
        rowptr, csr, (const float4*)bufA, dinv, b2, batch, nullptr, psum);

    k_head<<<NG, 64, 0, stream>>>(psum, batch, lw1, lb1, lw2, lb2, out);
}

// Round 7
// 316.765 us; speedup vs baseline: 5.3303x; 1.2392x over previous
//
#include <hip/hip_runtime.h>

static constexpr int NN  = 100000;   // nodes
static constexpr int NE  = 1600000;  // edges
static constexpr int NG  = 1000;     // graphs
static constexpr int D   = 64;       // D_IN = D_HID
static constexpr int DH  = 32;       // head hidden
static constexpr int DO  = 8;        // out dim
static constexpr int BKT = 128;      // nodes per bucket (7 bits)
static constexpr int NBK = (NN + BKT - 1) / BKT;     // 782
static constexpr int CHUNK = 4096;                   // edges per chunk block
static constexpr int NCH = (NE + CHUNK - 1) / CHUNK; // 391

// ---- bf16 helpers (bit-level; values here are never NaN/inf) ----
__device__ __forceinline__ float b2f(unsigned short u) {
    return __uint_as_float(((unsigned int)u) << 16);
}
__device__ __forceinline__ unsigned short f2b(float f) {   // round-to-nearest-even
    unsigned int u = __float_as_uint(f);
    u += 0x7FFFu + ((u >> 16) & 1u);
    return (unsigned short)(u >> 16);
}

// per-chunk LDS histogram of dst buckets -> count matrix (no global atomics)
__global__ __launch_bounds__(512) void
k_hist(const int* __restrict__ dst, int* __restrict__ cntmat) {
    __shared__ int lcnt[NBK];
    int t = threadIdx.x;
    long base = (long)blockIdx.x * CHUNK;
    for (int b = t; b < NBK; b += 512) lcnt[b] = 0;
    __syncthreads();
#pragma unroll
    for (int j = 0; j < 8; ++j) {
        long i = base + j * 512 + t;
        if (i < NE) atomicAdd(&lcnt[dst[i] >> 7], 1);   // LDS int atomic
    }
    __syncthreads();
    for (int b = t; b < NBK; b += 512)
        cntmat[blockIdx.x * NBK + b] = lcnt[b];
}

// bucket totals = column sums of cntmat
__global__ void k_colsum(const int* __restrict__ cntmat, int* __restrict__ bsum) {
    int b = blockIdx.x;
    int t = threadIdx.x;  // 64
    int s = 0;
    for (int c = t; c < NCH; c += 64) s += cntmat[c * NBK + b];
    for (int o = 32; o; o >>= 1) s += __shfl_down(s, o);
    if (t == 0) bsum[b] = s;
}

// single-block exclusive scan of NBK bucket totals -> boffs (+NE sentinel)
__global__ void k_scan(const int* __restrict__ bsum, int* __restrict__ boffs) {
    __shared__ int s[1024];
    int t = threadIdx.x;
    int v = (t < NBK) ? bsum[t] : 0;
    s[t] = v;
    __syncthreads();
    for (int o = 1; o < 1024; o <<= 1) {
        int a = (t >= o) ? s[t - o] : 0;
        __syncthreads();
        s[t] += a;
        __syncthreads();
    }
    if (t < NBK) boffs[t] = s[t] - v;
    if (t == 0) boffs[NBK] = NE;
}

// per-bucket scan across chunks: cntmat becomes exact write base per (chunk,bucket)
__global__ __launch_bounds__(512) void
k_rowscan(int* __restrict__ cntmat, const int* __restrict__ boffs) {
    __shared__ int s[512];
    int b = blockIdx.x, t = threadIdx.x;
    int v = (t < NCH) ? cntmat[t * NBK + b] : 0;
    s[t] = v;
    __syncthreads();
    for (int o = 1; o < 512; o <<= 1) {
        int a = (t >= o) ? s[t - o] : 0;
        __syncthreads();
        s[t] += a;
        __syncthreads();
    }
    if (t < NCH) cntmat[t * NBK + b] = boffs[b] + s[t] - v;
}

// binning with precomputed bases: zero global atomics.
// packed edge = src*128 + (dst & 127), grouped by bucket dst>>7
__global__ __launch_bounds__(512) void
k_bin(const int* __restrict__ src, const int* __restrict__ dst,
      const int* __restrict__ cntmat, int* __restrict__ ebuf) {
    __shared__ int lcnt[NBK];
    __shared__ int lbase[NBK];
    int t = threadIdx.x;
    long base = (long)blockIdx.x * CHUNK;
    for (int b = t; b < NBK; b += 512) lcnt[b] = 0;
    __syncthreads();
    int pk[8], bk[8], of[8];
#pragma unroll
    for (int j = 0; j < 8; ++j) {
        long i = base + j * 512 + t;
        if (i < NE) {
            int d = dst[i];
            bk[j] = d >> 7;
            pk[j] = src[i] * BKT + (d & (BKT - 1));
            of[j] = atomicAdd(&lcnt[bk[j]], 1);
        } else bk[j] = -1;
    }
    __syncthreads();
    for (int b = t; b < NBK; b += 512) lbase[b] = cntmat[blockIdx.x * NBK + b];
    __syncthreads();
#pragma unroll
    for (int j = 0; j < 8; ++j)
        if (bk[j] >= 0) ebuf[lbase[bk[j]] + of[j]] = pk[j];
}

// per-bucket: LDS histogram of local idx -> rowptr/dinv, then exact CSR scatter
__global__ __launch_bounds__(256) void
k_csrdeg(const int* __restrict__ boffs, const int* __restrict__ ebuf,
         int* __restrict__ rowptr, float* __restrict__ dinv, int* __restrict__ csr) {
    __shared__ int hist[BKT];
    __shared__ int sc[BKT];
    __shared__ int lcur[BKT];
    int b = blockIdx.x, t = threadIdx.x;
    if (t < BKT) hist[t] = 0;
    __syncthreads();
    int beg = boffs[b], end = boffs[b + 1];
    for (int e = beg + t; e < end; e += 256)
        atomicAdd(&hist[ebuf[e] & (BKT - 1)], 1);
    __syncthreads();
    if (t < BKT) sc[t] = hist[t];
    __syncthreads();
    for (int o = 1; o < BKT; o <<= 1) {
        int a = (t < BKT && t >= o) ? sc[t - o] : 0;
        __syncthreads();
        if (t < BKT) sc[t] += a;
        __syncthreads();
    }
    int v0 = b * BKT;
    if (t < BKT) {
        int v = v0 + t;
        if (v < NN) {
            int excl = beg + sc[t] - hist[t];
            rowptr[v] = excl;
            dinv[v]   = rsqrtf((float)(hist[t] + 1));
            lcur[t]   = excl;
        }
    }
    if (b == NBK - 1 && t == 0) rowptr[NN] = NE;
    __syncthreads();
    for (int e = beg + t; e < end; e += 256) {
        int p = ebuf[e];
        int slot = atomicAdd(&lcur[p & (BKT - 1)], 1);
        csr[slot] = p >> 7;
    }
}

// out[n][j] = bf16( dinv[n] * sum_k in[n][k] * W[k][j] )   (16 rows/block)
template <typename TIN>
__global__ void k_mm_scale(const TIN* __restrict__ in, const float* __restrict__ W,
                           const float* __restrict__ dinv,
                           unsigned short* __restrict__ out) {
    __shared__ float Ws[D * D];       // 16 KB
    __shared__ float rows[16][D];
    int t = threadIdx.x;              // 1024 threads: 16 rows x 64 cols
    for (int i = t; i < D * D; i += 1024) Ws[i] = W[i];
    int r = t >> 6, j = t & 63;
    int n = blockIdx.x * 16 + r;      // NN % 16 == 0
    float xv;
    if constexpr (sizeof(TIN) == 2) xv = b2f(((const unsigned short*)in)[(long)n * D + j]);
    else                            xv = ((const float*)in)[(long)n * D + j];
    rows[r][j] = xv;
    __syncthreads();
    float acc = 0.f;
#pragma unroll
    for (int k = 0; k < D; ++k) acc += rows[r][k] * Ws[k * D + j];
    out[(long)n * D + j] = f2b(acc * dinv[n]);
}

// CSR pull aggregation on bf16 rows. lane = slot(3b) x fg(3b); each lane gathers
// uint4 = 8 bf16 (16 B) -> 1 KB per wave instr over 8 nodes. One node per slot.
// RELU=true: layer 1. RELU=false: layer 2 (h2 rows, pooled later).
template <bool RELU>
__global__ __launch_bounds__(256) void
k_agg(const int* __restrict__ rowptr, const int* __restrict__ csr,
      const uint4* __restrict__ g4, const float* __restrict__ dinv,
      const float* __restrict__ bias, uint4* __restrict__ out4) {
    int t = threadIdx.x;
    int lane = t & 63;
    int fg = lane & 7;           // dims [fg*8, fg*8+8)
    int slot = lane >> 3;        // 0..7
    int wid = blockIdx.x * 4 + (t >> 6);
    int v = wid * 8 + slot;      // 12500 * 8 == NN exactly, no bounds checks
    int beg = rowptr[v];
    int len = rowptr[v + 1] - beg;
    int lmax = len;
    lmax = max(lmax, __shfl_xor(lmax, 8));
    lmax = max(lmax, __shfl_xor(lmax, 16));
    lmax = max(lmax, __shfl_xor(lmax, 32));
    float acc[8];
    {   // self-loop term
        uint4 sv = g4[(long)v * 8 + fg];
        acc[0] = __uint_as_float(sv.x << 16); acc[1] = __uint_as_float(sv.x & 0xFFFF0000u);
        acc[2] = __uint_as_float(sv.y << 16); acc[3] = __uint_as_float(sv.y & 0xFFFF0000u);
        acc[4] = __uint_as_float(sv.z << 16); acc[5] = __uint_as_float(sv.z & 0xFFFF0000u);
        acc[6] = __uint_as_float(sv.w << 16); acc[7] = __uint_as_float(sv.w & 0xFFFF0000u);
    }
    for (int e = 0; e < lmax; e += 4) {
#pragma unroll
        for (int j = 0; j < 4; ++j) {
            int ee = e + j;
            float m = (ee < len) ? 1.f : 0.f;
            int idx = beg + ((ee < len) ? ee : 0);
            int srcn = csr[idx];
            uint4 a = g4[(long)srcn * 8 + fg];
            acc[0] += m * __uint_as_float(a.x << 16);
            acc[1] += m * __uint_as_float(a.x & 0xFFFF0000u);
            acc[2] += m * __uint_as_float(a.y << 16);
            acc[3] += m * __uint_as_float(a.y & 0xFFFF0000u);
            acc[4] += m * __uint_as_float(a.z << 16);
            acc[5] += m * __uint_as_float(a.z & 0xFFFF0000u);
            acc[6] += m * __uint_as_float(a.w << 16);
            acc[7] += m * __uint_as_float(a.w & 0xFFFF0000u);
        }
    }
    float dv = dinv[v];
    unsigned short ob[8];
#pragma unroll
    for (int k = 0; k < 8; ++k) {
        float x = acc[k] * dv + bias[fg * 8 + k];
        if (RELU) x = fmaxf(x, 0.f);
        ob[k] = f2b(x);
    }
    uint4 o;
    o.x = (unsigned int)ob[0] | ((unsigned int)ob[1] << 16);
    o.y = (unsigned int)ob[2] | ((unsigned int)ob[3] << 16);
    o.z = (unsigned int)ob[4] | ((unsigned int)ob[5] << 16);
    o.w = (unsigned int)ob[6] | ((unsigned int)ob[7] << 16);
    out4[(long)v * 8 + fg] = o;
}

// fused mean-pool + MLP head, one wave per graph, zero atomics (batch sorted)
__global__ void k_poolhead(const unsigned short* __restrict__ h,
                           const int* __restrict__ batch,
                           const float* __restrict__ lw1, const float* __restrict__ lb1,
                           const float* __restrict__ lw2, const float* __restrict__ lb2,
                           float* __restrict__ out) {
    __shared__ float pl[D];
    __shared__ float z[DH];
    int g = blockIdx.x;
    int t = threadIdx.x;  // 64, lane = dim
    int lo = 0, hi = NN;
    while (lo < hi) { int m = (lo + hi) >> 1; if (batch[m] < g) lo = m + 1; else hi = m; }
    int lb = lo;
    hi = NN;
    while (lo < hi) { int m = (lo + hi) >> 1; if (batch[m] < g + 1) lo = m + 1; else hi = m; }
    int ub = lo;
    float s = 0.f;
    int n = lb;
    for (; n + 4 <= ub; n += 4) {
        float a0 = b2f(h[(long)(n + 0) * D + t]);
        float a1 = b2f(h[(long)(n + 1) * D + t]);
        float a2 = b2f(h[(long)(n + 2) * D + t]);
        float a3 = b2f(h[(long)(n + 3) * D + t]);
        s += a0 + a1 + a2 + a3;
    }
    for (; n < ub; ++n) s += b2f(h[(long)n * D + t]);
    pl[t] = s / fmaxf((float)(ub - lb), 1.0f);
    __syncthreads();
    if (t < DH) {
        float a = lb1[t];
#pragma unroll
        for (int k = 0; k < D; ++k) a += pl[k] * lw1[k * DH + t];
        z[t] = fmaxf(a, 0.f);
    }
    __syncthreads();
    if (t < DO) {
        float a = lb2[t];
#pragma unroll
        for (int j = 0; j < DH; ++j) a += z[j] * lw2[j * DO + t];
        out[g * DO + t] = a;
    }
}

extern "C" void kernel_launch(void* const* d_in, const int* in_sizes, int n_in,
                              void* d_out, int out_size, void* d_ws, size_t ws_size,
                              hipStream_t stream) {
    const float* x    = (const float*)d_in[0];
    const int*   ei   = (const int*)  d_in[1];
    const int*   batch= (const int*)  d_in[2];
    const float* W1   = (const float*)d_in[3];
    const float* b1   = (const float*)d_in[4];
    const float* W2   = (const float*)d_in[5];
    const float* b2   = (const float*)d_in[6];
    const float* lw1  = (const float*)d_in[7];
    const float* lb1  = (const float*)d_in[8];
    const float* lw2  = (const float*)d_in[9];
    const float* lb2  = (const float*)d_in[10];
    float* out = (float*)d_out;

    const int* srcv = ei;        // edge_index[0]
    const int* dstv = ei + NE;   // edge_index[1]

    char* ws = (char*)d_ws;
    size_t off = 0;
    auto alloc = [&](size_t bytes) {
        void* p = ws + off;
        off = (off + bytes + 255) & ~(size_t)255;
        return p;
    };
    int*   cntmat = (int*)  alloc((size_t)NCH * NBK * 4);  // 1.22 MB
    int*   bsum   = (int*)  alloc((size_t)NBK * 4);
    int*   boffs  = (int*)  alloc((size_t)(NBK + 1) * 4);
    int*   rowptr = (int*)  alloc((size_t)(NN + 1) * 4);
    int*   csr    = (int*)  alloc((size_t)NE * 4);         // 6.4 MB
    float* dinv   = (float*)alloc((size_t)NN * 4);
    unsigned short* bufA = (unsigned short*)alloc((size_t)NN * D * 2);  // 12.8 MB bf16
    unsigned short* bufB = (unsigned short*)alloc((size_t)NN * D * 2);  // 12.8 MB bf16
    int*   ebuf   = (int*)bufA;  // binning scratch (6.4 MB); dead before bufA written

    k_hist   <<<NCH, 512, 0, stream>>>(dstv, cntmat);
    k_colsum <<<NBK, 64, 0, stream>>>(cntmat, bsum);
    k_scan   <<<1, 1024, 0, stream>>>(bsum, boffs);
    k_rowscan<<<NBK, 512, 0, stream>>>(cntmat, boffs);
    k_bin    <<<NCH, 512, 0, stream>>>(srcv, dstv, cntmat, ebuf);
    k_csrdeg <<<NBK, 256, 0, stream>>>(boffs, ebuf, rowptr, dinv, csr);

    // layer 1: g1 = bf16((x @ W1) * dinv) -> bufA ; h1 = relu(agg) -> bufB
    k_mm_scale<float><<<NN / 16, 1024, 0, stream>>>(x, W1, dinv, bufA);
    k_agg<true><<<NN / 32, 256, 0, stream>>>(
        rowptr, csr, (const uint4*)bufA, dinv, b1, (uint4*)bufB);

    // layer 2: g2 = bf16((h1 @ W2) * dinv) -> bufA ; h2 = agg -> bufB
    k_mm_scale<unsigned short><<<NN / 16, 1024, 0, stream>>>(bufB, W2, dinv, bufA);
    k_agg<false><<<NN / 32, 256, 0, stream>>>(
        rowptr, csr, (const uint4*)bufA, dinv, b2, (uint4*)bufB);

    k_poolhead<<<NG, 64, 0, stream>>>(bufB, batch, lw1, lb1, lw2, lb2, out);
}

// Round 8
// 238.415 us; speedup vs baseline: 7.0821x; 1.3286x over previous
//
#include <hip/hip_runtime.h>

static constexpr int NN  = 100000;   // nodes
static constexpr int NE  = 1600000;  // edges
static constexpr int NG  = 1000;     // graphs
static constexpr int D   = 64;       // D_IN = D_HID
static constexpr int DH  = 32;       // head hidden
static constexpr int DO  = 8;        // out dim
static constexpr int BKT = 128;      // nodes per bucket (7 bits)
static constexpr int NBK = (NN + BKT - 1) / BKT;     // 782
static constexpr int CHUNK = 4096;                   // edges per chunk block
static constexpr int NCH = (NE + CHUNK - 1) / CHUNK; // 391

typedef __attribute__((ext_vector_type(8))) short bf16x8;
typedef __attribute__((ext_vector_type(4))) float f32x4;

// ---- bf16 helpers (bit-level; values here are never NaN/inf) ----
__device__ __forceinline__ float b2f(unsigned short u) {
    return __uint_as_float(((unsigned int)u) << 16);
}
__device__ __forceinline__ unsigned short f2b(float f) {   // round-to-nearest-even
    unsigned int u = __float_as_uint(f);
    u += 0x7FFFu + ((u >> 16) & 1u);
    return (unsigned short)(u >> 16);
}
__device__ __forceinline__ uint4 pack8(const unsigned short* h) {
    uint4 u;
    u.x = (unsigned)h[0] | ((unsigned)h[1] << 16);
    u.y = (unsigned)h[2] | ((unsigned)h[3] << 16);
    u.z = (unsigned)h[4] | ((unsigned)h[5] << 16);
    u.w = (unsigned)h[6] | ((unsigned)h[7] << 16);
    return u;
}

// per-chunk LDS histogram of dst buckets -> count matrix (no global atomics)
__global__ __launch_bounds__(512) void
k_hist(const int* __restrict__ dst, int* __restrict__ cntmat) {
    __shared__ int lcnt[NBK];
    int t = threadIdx.x;
    long base = (long)blockIdx.x * CHUNK;
    for (int b = t; b < NBK; b += 512) lcnt[b] = 0;
    __syncthreads();
#pragma unroll
    for (int j = 0; j < 8; ++j) {
        long i = base + j * 512 + t;
        if (i < NE) atomicAdd(&lcnt[dst[i] >> 7], 1);   // LDS int atomic
    }
    __syncthreads();
    for (int b = t; b < NBK; b += 512)
        cntmat[blockIdx.x * NBK + b] = lcnt[b];
}

// bucket totals = column sums of cntmat
__global__ void k_colsum(const int* __restrict__ cntmat, int* __restrict__ bsum) {
    int b = blockIdx.x;
    int t = threadIdx.x;  // 64
    int s = 0;
    for (int c = t; c < NCH; c += 64) s += cntmat[c * NBK + b];
    for (int o = 32; o; o >>= 1) s += __shfl_down(s, o);
    if (t == 0) bsum[b] = s;
}

// single-block exclusive scan of NBK bucket totals -> boffs (+NE sentinel)
__global__ void k_scan(const int* __restrict__ bsum, int* __restrict__ boffs) {
    __shared__ int s[1024];
    int t = threadIdx.x;
    int v = (t < NBK) ? bsum[t] : 0;
    s[t] = v;
    __syncthreads();
    for (int o = 1; o < 1024; o <<= 1) {
        int a = (t >= o) ? s[t - o] : 0;
        __syncthreads();
        s[t] += a;
        __syncthreads();
    }
    if (t < NBK) boffs[t] = s[t] - v;
    if (t == 0) boffs[NBK] = NE;
}

// per-bucket scan across chunks: cntmat becomes exact write base per (chunk,bucket)
__global__ __launch_bounds__(512) void
k_rowscan(int* __restrict__ cntmat, const int* __restrict__ boffs) {
    __shared__ int s[512];
    int b = blockIdx.x, t = threadIdx.x;
    int v = (t < NCH) ? cntmat[t * NBK + b] : 0;
    s[t] = v;
    __syncthreads();
    for (int o = 1; o < 512; o <<= 1) {
        int a = (t >= o) ? s[t - o] : 0;
        __syncthreads();
        s[t] += a;
        __syncthreads();
    }
    if (t < NCH) cntmat[t * NBK + b] = boffs[b] + s[t] - v;
}

// binning with precomputed bases: zero global atomics.
__global__ __launch_bounds__(512) void
k_bin(const int* __restrict__ src, const int* __restrict__ dst,
      const int* __restrict__ cntmat, int* __restrict__ ebuf) {
    __shared__ int lcnt[NBK];
    __shared__ int lbase[NBK];
    int t = threadIdx.x;
    long base = (long)blockIdx.x * CHUNK;
    for (int b = t; b < NBK; b += 512) lcnt[b] = 0;
    __syncthreads();
    int pk[8], bk[8], of[8];
#pragma unroll
    for (int j = 0; j < 8; ++j) {
        long i = base + j * 512 + t;
        if (i < NE) {
            int d = dst[i];
            bk[j] = d >> 7;
            pk[j] = src[i] * BKT + (d & (BKT - 1));
            of[j] = atomicAdd(&lcnt[bk[j]], 1);
        } else bk[j] = -1;
    }
    __syncthreads();
    for (int b = t; b < NBK; b += 512) lbase[b] = cntmat[blockIdx.x * NBK + b];
    __syncthreads();
#pragma unroll
    for (int j = 0; j < 8; ++j)
        if (bk[j] >= 0) ebuf[lbase[bk[j]] + of[j]] = pk[j];
}

// per-bucket: LDS histogram of local idx -> rowptr/dinv, then exact CSR scatter
__global__ __launch_bounds__(256) void
k_csrdeg(const int* __restrict__ boffs, const int* __restrict__ ebuf,
         int* __restrict__ rowptr, float* __restrict__ dinv, int* __restrict__ csr) {
    __shared__ int hist[BKT];
    __shared__ int sc[BKT];
    __shared__ int lcur[BKT];
    int b = blockIdx.x, t = threadIdx.x;
    if (t < BKT) hist[t] = 0;
    __syncthreads();
    int beg = boffs[b], end = boffs[b + 1];
    for (int e = beg + t; e < end; e += 256)
        atomicAdd(&hist[ebuf[e] & (BKT - 1)], 1);
    __syncthreads();
    if (t < BKT) sc[t] = hist[t];
    __syncthreads();
    for (int o = 1; o < BKT; o <<= 1) {
        int a = (t < BKT && t >= o) ? sc[t - o] : 0;
        __syncthreads();
        if (t < BKT) sc[t] += a;
        __syncthreads();
    }
    int v0 = b * BKT;
    if (t < BKT) {
        int v = v0 + t;
        if (v < NN) {
            int excl = beg + sc[t] - hist[t];
            rowptr[v] = excl;
            dinv[v]   = rsqrtf((float)(hist[t] + 1));
            lcur[t]   = excl;
        }
    }
    if (b == NBK - 1 && t == 0) rowptr[NN] = NE;
    __syncthreads();
    for (int e = beg + t; e < end; e += 256) {
        int p = ebuf[e];
        int slot = atomicAdd(&lcur[p & (BKT - 1)], 1);
        csr[slot] = p >> 7;
    }
}

// split W into transposed bf16 hi/lo: Wt[n][k] = W[k][n]. grid=2 (W1, W2).
__global__ void k_prepw(const float* __restrict__ W1, const float* __restrict__ W2,
                        unsigned short* __restrict__ wtbuf) {
    const float* W = blockIdx.x ? W2 : W1;
    unsigned short* WtHi = wtbuf + (size_t)blockIdx.x * 8192;
    unsigned short* WtLo = WtHi + 4096;
    int t = threadIdx.x;           // 256
    int n = t >> 2, k0 = (t & 3) * 16;
    unsigned short hi[16], lo[16];
#pragma unroll
    for (int i = 0; i < 16; ++i) {
        float v = W[(k0 + i) * 64 + n];
        hi[i] = f2b(v);
        lo[i] = f2b(v - b2f(hi[i]));
    }
    ((uint4*)WtHi)[n * 8 + (t & 3) * 2]     = pack8(hi);
    ((uint4*)WtHi)[n * 8 + (t & 3) * 2 + 1] = pack8(hi + 8);
    ((uint4*)WtLo)[n * 8 + (t & 3) * 2]     = pack8(lo);
    ((uint4*)WtLo)[n * 8 + (t & 3) * 2 + 1] = pack8(lo + 8);
}

// MFMA matmul: out[n][:] = bf16(dinv[n] * (A[n][:] @ W)), 64 nodes/block.
// Split-bf16: A@W = Ahi·Whi + Ahi·Wlo (+ Alo·Whi if SPLIT_A) — ~f32 accurate.
template <bool SPLIT_A>
__global__ __launch_bounds__(256) void
k_mm_mfma(const void* __restrict__ Ain, const unsigned short* __restrict__ wt,
          const float* __restrict__ dinv, uint4* __restrict__ out) {
    __shared__ unsigned short smem[4 * 64 * 72];   // 36864 B
    unsigned short* Ahi  = smem;
    unsigned short* Alo  = smem + 4608;
    unsigned short* WtHi = smem + 9216;
    unsigned short* WtLo = smem + 13824;
    int t = threadIdx.x;
    int r = t >> 2, cc = t & 3, c0 = cc * 16;
    long n0 = (long)blockIdx.x * 64;
    {   // stage Wt (hi/lo), coalesced
        const uint4* H = (const uint4*)wt;
        const uint4* L = (const uint4*)(wt + 4096);
        uint4* dh = (uint4*)&WtHi[r * 72 + c0];
        uint4* dl = (uint4*)&WtLo[r * 72 + c0];
        dh[0] = H[r * 8 + cc * 2]; dh[1] = H[r * 8 + cc * 2 + 1];
        dl[0] = L[r * 8 + cc * 2]; dl[1] = L[r * 8 + cc * 2 + 1];
    }
    {   // stage A (convert+split if f32 input)
        long n = n0 + r; if (n >= NN) n = NN - 1;
        if constexpr (SPLIT_A) {
            const float4* X = (const float4*)Ain;
            unsigned short hi[16], lo[16];
#pragma unroll
            for (int i = 0; i < 4; ++i) {
                float4 v = X[n * 16 + cc * 4 + i];
                float vv[4] = {v.x, v.y, v.z, v.w};
#pragma unroll
                for (int j = 0; j < 4; ++j) {
                    unsigned short h = f2b(vv[j]);
                    hi[i * 4 + j] = h;
                    lo[i * 4 + j] = f2b(vv[j] - b2f(h));
                }
            }
            uint4* dh = (uint4*)&Ahi[r * 72 + c0];
            uint4* dl = (uint4*)&Alo[r * 72 + c0];
            dh[0] = pack8(hi); dh[1] = pack8(hi + 8);
            dl[0] = pack8(lo); dl[1] = pack8(lo + 8);
        } else {
            const uint4* X = (const uint4*)Ain;
            uint4* dh = (uint4*)&Ahi[r * 72 + c0];
            dh[0] = X[n * 8 + cc * 2]; dh[1] = X[n * 8 + cc * 2 + 1];
        }
    }
    __syncthreads();
    int lane = t & 63, w = t >> 6;
    int q = lane >> 4, m = lane & 15;
    f32x4 acc[4] = {{0.f,0.f,0.f,0.f},{0.f,0.f,0.f,0.f},{0.f,0.f,0.f,0.f},{0.f,0.f,0.f,0.f}};
#pragma unroll
    for (int s = 0; s < 2; ++s) {
        int ko = s * 32 + q * 8;
        bf16x8 ah = *(const bf16x8*)&Ahi[(w * 16 + m) * 72 + ko];
        bf16x8 al{};
        if constexpr (SPLIT_A) al = *(const bf16x8*)&Alo[(w * 16 + m) * 72 + ko];
#pragma unroll
        for (int c = 0; c < 4; ++c) {
            bf16x8 bh = *(const bf16x8*)&WtHi[(c * 16 + m) * 72 + ko];
            bf16x8 bl = *(const bf16x8*)&WtLo[(c * 16 + m) * 72 + ko];
            acc[c] = __builtin_amdgcn_mfma_f32_16x16x32_bf16(ah, bh, acc[c], 0, 0, 0);
            acc[c] = __builtin_amdgcn_mfma_f32_16x16x32_bf16(ah, bl, acc[c], 0, 0, 0);
            if constexpr (SPLIT_A)
                acc[c] = __builtin_amdgcn_mfma_f32_16x16x32_bf16(al, bh, acc[c], 0, 0, 0);
        }
    }
    __syncthreads();
    float* Ct = (float*)smem;   // 64 x 68 f32 tile (17408 B, overlaps dead A/Wt)
#pragma unroll
    for (int c = 0; c < 4; ++c)
#pragma unroll
        for (int rr = 0; rr < 4; ++rr)
            Ct[(w * 16 + q * 4 + rr) * 68 + c * 16 + m] = acc[c][rr];
    __syncthreads();
    {
        long n = n0 + r;
        if (n < NN) {
            float dv = dinv[n];
            unsigned short ob[16];
#pragma unroll
            for (int i = 0; i < 4; ++i) {
                float4 v = *(const float4*)&Ct[r * 68 + c0 + i * 4];
                ob[i * 4 + 0] = f2b(v.x * dv); ob[i * 4 + 1] = f2b(v.y * dv);
                ob[i * 4 + 2] = f2b(v.z * dv); ob[i * 4 + 3] = f2b(v.w * dv);
            }
            out[n * 8 + cc * 2]     = pack8(ob);
            out[n * 8 + cc * 2 + 1] = pack8(ob + 8);
        }
    }
}

// CSR pull aggregation on bf16 rows. lane = slot(3b) x fg(3b); each lane gathers
// uint4 = 8 bf16 (16 B). One node per slot. RELU=true: layer1.
template <bool RELU>
__global__ __launch_bounds__(256) void
k_agg(const int* __restrict__ rowptr, const int* __restrict__ csr,
      const uint4* __restrict__ g4, const float* __restrict__ dinv,
      const float* __restrict__ bias, uint4* __restrict__ out4) {
    int t = threadIdx.x;
    int lane = t & 63;
    int fg = lane & 7;           // dims [fg*8, fg*8+8)
    int slot = lane >> 3;        // 0..7
    int wid = blockIdx.x * 4 + (t >> 6);
    int v = wid * 8 + slot;      // 12500 * 8 == NN exactly
    int beg = rowptr[v];
    int len = rowptr[v + 1] - beg;
    int lmax = len;
    lmax = max(lmax, __shfl_xor(lmax, 8));
    lmax = max(lmax, __shfl_xor(lmax, 16));
    lmax = max(lmax, __shfl_xor(lmax, 32));
    float acc[8];
    {   // self-loop term
        uint4 sv = g4[(long)v * 8 + fg];
        acc[0] = __uint_as_float(sv.x << 16); acc[1] = __uint_as_float(sv.x & 0xFFFF0000u);
        acc[2] = __uint_as_float(sv.y << 16); acc[3] = __uint_as_float(sv.y & 0xFFFF0000u);
        acc[4] = __uint_as_float(sv.z << 16); acc[5] = __uint_as_float(sv.z & 0xFFFF0000u);
        acc[6] = __uint_as_float(sv.w << 16); acc[7] = __uint_as_float(sv.w & 0xFFFF0000u);
    }
    for (int e = 0; e < lmax; e += 4) {
#pragma unroll
        for (int j = 0; j < 4; ++j) {
            int ee = e + j;
            float m = (ee < len) ? 1.f : 0.f;
            int idx = beg + ((ee < len) ? ee : 0);
            int srcn = csr[idx];
            uint4 a = g4[(long)srcn * 8 + fg];
            acc[0] += m * __uint_as_float(a.x << 16);
            acc[1] += m * __uint_as_float(a.x & 0xFFFF0000u);
            acc[2] += m * __uint_as_float(a.y << 16);
            acc[3] += m * __uint_as_float(a.y & 0xFFFF0000u);
            acc[4] += m * __uint_as_float(a.z << 16);
            acc[5] += m * __uint_as_float(a.z & 0xFFFF0000u);
            acc[6] += m * __uint_as_float(a.w << 16);
            acc[7] += m * __uint_as_float(a.w & 0xFFFF0000u);
        }
    }
    float dv = dinv[v];
    unsigned short ob[8];
#pragma unroll
    for (int k = 0; k < 8; ++k) {
        float x = acc[k] * dv + bias[fg * 8 + k];
        if (RELU) x = fmaxf(x, 0.f);
        ob[k] = f2b(x);
    }
    out4[(long)v * 8 + fg] = pack8(ob);
}

// fused mean-pool + MLP head, one wave per graph, zero atomics (batch sorted)
__global__ void k_poolhead(const unsigned short* __restrict__ h,
                           const int* __restrict__ batch,
                           const float* __restrict__ lw1, const float* __restrict__ lb1,
                           const float* __restrict__ lw2, const float* __restrict__ lb2,
                           float* __restrict__ out) {
    __shared__ float pl[D];
    __shared__ float z[DH];
    int g = blockIdx.x;
    int t = threadIdx.x;  // 64, lane = dim
    int lo = 0, hi = NN;
    while (lo < hi) { int m = (lo + hi) >> 1; if (batch[m] < g) lo = m + 1; else hi = m; }
    int lb = lo;
    hi = NN;
    while (lo < hi) { int m = (lo + hi) >> 1; if (batch[m] < g + 1) lo = m + 1; else hi = m; }
    int ub = lo;
    float s = 0.f;
    int n = lb;
    for (; n + 4 <= ub; n += 4) {
        float a0 = b2f(h[(long)(n + 0) * D + t]);
        float a1 = b2f(h[(long)(n + 1) * D + t]);
        float a2 = b2f(h[(long)(n + 2) * D + t]);
        float a3 = b2f(h[(long)(n + 3) * D + t]);
        s += a0 + a1 + a2 + a3;
    }
    for (; n < ub; ++n) s += b2f(h[(long)n * D + t]);
    pl[t] = s / fmaxf((float)(ub - lb), 1.0f);
    __syncthreads();
    if (t < DH) {
        float a = lb1[t];
#pragma unroll
        for (int k = 0; k < D; ++k) a += pl[k] * lw1[k * DH + t];
        z[t] = fmaxf(a, 0.f);
    }
    __syncthreads();
    if (t < DO) {
        float a = lb2[t];
#pragma unroll
        for (int j = 0; j < DH; ++j) a += z[j] * lw2[j * DO + t];
        out[g * DO + t] = a;
    }
}

extern "C" void kernel_launch(void* const* d_in, const int* in_sizes, int n_in,
                              void* d_out, int out_size, void* d_ws, size_t ws_size,
                              hipStream_t stream) {
    const float* x    = (const float*)d_in[0];
    const int*   ei   = (const int*)  d_in[1];
    const int*   batch= (const int*)  d_in[2];
    const float* W1   = (const float*)d_in[3];
    const float* b1   = (const float*)d_in[4];
    const float* W2   = (const float*)d_in[5];
    const float* b2   = (const float*)d_in[6];
    const float* lw1  = (const float*)d_in[7];
    const float* lb1  = (const float*)d_in[8];
    const float* lw2  = (const float*)d_in[9];
    const float* lb2  = (const float*)d_in[10];
    float* out = (float*)d_out;

    const int* srcv = ei;        // edge_index[0]
    const int* dstv = ei + NE;   // edge_index[1]

    char* ws = (char*)d_ws;
    size_t off = 0;
    auto alloc = [&](size_t bytes) {
        void* p = ws + off;
        off = (off + bytes + 255) & ~(size_t)255;
        return p;
    };
    int*   cntmat = (int*)  alloc((size_t)NCH * NBK * 4);  // 1.22 MB
    int*   bsum   = (int*)  alloc((size_t)NBK * 4);
    int*   boffs  = (int*)  alloc((size_t)(NBK + 1) * 4);
    int*   rowptr = (int*)  alloc((size_t)(NN + 1) * 4);
    int*   csr    = (int*)  alloc((size_t)NE * 4);         // 6.4 MB
    float* dinv   = (float*)alloc((size_t)NN * 4);
    unsigned short* wtbuf = (unsigned short*)alloc((size_t)4 * 4096 * 2);  // 32 KB
    unsigned short* bufA = (unsigned short*)alloc((size_t)NN * D * 2);    // 12.8 MB
    unsigned short* bufB = (unsigned short*)alloc((size_t)NN * D * 2);    // 12.8 MB
    int*   ebuf   = (int*)bufA;  // binning scratch (6.4 MB); dead before bufA written

    k_hist   <<<NCH, 512, 0, stream>>>(dstv, cntmat);
    k_colsum <<<NBK, 64, 0, stream>>>(cntmat, bsum);
    k_scan   <<<1, 1024, 0, stream>>>(bsum, boffs);
    k_rowscan<<<NBK, 512, 0, stream>>>(cntmat, boffs);
    k_bin    <<<NCH, 512, 0, stream>>>(srcv, dstv, cntmat, ebuf);
    k_csrdeg <<<NBK, 256, 0, stream>>>(boffs, ebuf, rowptr, dinv, csr);
    k_prepw  <<<2, 256, 0, stream>>>(W1, W2, wtbuf);

    const int MMB = (NN + 63) / 64;   // 1563

    // layer 1: g1 = bf16((x @ W1) * dinv) -> bufA ; h1 = relu(agg) -> bufB
    k_mm_mfma<true><<<MMB, 256, 0, stream>>>(x, wtbuf, dinv, (uint4*)bufA);
    k_agg<true><<<NN / 32, 256, 0, stream>>>(
        rowptr, csr, (const uint4*)bufA, dinv, b1, (uint4*)bufB);

    // layer 2: g2 = bf16((h1 @ W2) * dinv) -> bufA ; h2 = agg -> bufB
    k_mm_mfma<false><<<MMB, 256, 0, stream>>>(bufB, wtbuf + 8192, dinv, (uint4*)bufA);
    k_agg<false><<<NN / 32, 256, 0, stream>>>(
        rowptr, csr, (const uint4*)bufA, dinv, b2, (uint4*)bufB);

    k_poolhead<<<NG, 64, 0, stream>>>(bufB, batch, lw1, lb1, lw2, lb2, out);
}

// Round 9
// 225.390 us; speedup vs baseline: 7.4913x; 1.0578x over previous
//
#include <hip/hip_runtime.h>

static constexpr int NN  = 100000;   // nodes
static constexpr int NE  = 1600000;  // edges
static constexpr int NG  = 1000;     // graphs
static constexpr int D   = 64;       // D_IN = D_HID
static constexpr int DH  = 32;       // head hidden
static constexpr int DO  = 8;        // out dim
static constexpr int BKT = 128;      // nodes per bucket (7 bits)
static constexpr int NBK = (NN + BKT - 1) / BKT;     // 782
static constexpr int CHUNK = 4096;                   // edges per chunk block
static constexpr int NCH = (NE + CHUNK - 1) / CHUNK; // 391

typedef __attribute__((ext_vector_type(8))) short bf16x8;
typedef __attribute__((ext_vector_type(4))) float f32x4;

// ---- bf16 helpers (bit-level; values here are never NaN/inf) ----
__device__ __forceinline__ float b2f(unsigned short u) {
    return __uint_as_float(((unsigned int)u) << 16);
}
__device__ __forceinline__ unsigned short f2b(float f) {   // round-to-nearest-even
    unsigned int u = __float_as_uint(f);
    u += 0x7FFFu + ((u >> 16) & 1u);
    return (unsigned short)(u >> 16);
}
__device__ __forceinline__ uint4 pack8(const unsigned short* h) {
    uint4 u;
    u.x = (unsigned)h[0] | ((unsigned)h[1] << 16);
    u.y = (unsigned)h[2] | ((unsigned)h[3] << 16);
    u.z = (unsigned)h[4] | ((unsigned)h[5] << 16);
    u.w = (unsigned)h[6] | ((unsigned)h[7] << 16);
    return u;
}

// per-chunk LDS histogram of dst buckets -> count matrix (no global atomics)
__global__ __launch_bounds__(512) void
k_hist(const int* __restrict__ dst, int* __restrict__ cntmat) {
    __shared__ int lcnt[NBK];
    int t = threadIdx.x;
    long base = (long)blockIdx.x * CHUNK;
    for (int b = t; b < NBK; b += 512) lcnt[b] = 0;
    __syncthreads();
#pragma unroll
    for (int j = 0; j < 8; ++j) {
        long i = base + j * 512 + t;
        if (i < NE) atomicAdd(&lcnt[dst[i] >> 7], 1);   // LDS int atomic
    }
    __syncthreads();
    for (int b = t; b < NBK; b += 512)
        cntmat[blockIdx.x * NBK + b] = lcnt[b];
}

// fused: per-bucket scan over chunks (cntmat -> local exclusive prefix, no boffs)
// + bucket total to bsum. k_bin adds boffs[b] itself.
__global__ __launch_bounds__(512) void
k_colsum_rowscan(int* __restrict__ cntmat, int* __restrict__ bsum) {
    __shared__ int s[512];
    int b = blockIdx.x, t = threadIdx.x;
    int v = (t < NCH) ? cntmat[t * NBK + b] : 0;
    s[t] = v;
    __syncthreads();
    for (int o = 1; o < 512; o <<= 1) {
        int a = (t >= o) ? s[t - o] : 0;
        __syncthreads();
        s[t] += a;
        __syncthreads();
    }
    if (t < NCH) cntmat[t * NBK + b] = s[t] - v;   // local exclusive prefix
    if (t == 0) bsum[b] = s[511];                  // bucket total
}

// fused: block 0 = exclusive scan of NBK bucket totals -> boffs (+NE sentinel);
// blocks 1,2 = split W into transposed bf16 hi/lo (W1, W2).
__global__ __launch_bounds__(1024) void
k_scan_prepw(const int* __restrict__ bsum, int* __restrict__ boffs,
             const float* __restrict__ W1, const float* __restrict__ W2,
             unsigned short* __restrict__ wtbuf) {
    int t = threadIdx.x;
    if (blockIdx.x == 0) {
        __shared__ int s[1024];
        int v = (t < NBK) ? bsum[t] : 0;
        s[t] = v;
        __syncthreads();
        for (int o = 1; o < 1024; o <<= 1) {
            int a = (t >= o) ? s[t - o] : 0;
            __syncthreads();
            s[t] += a;
            __syncthreads();
        }
        if (t < NBK) boffs[t] = s[t] - v;
        if (t == 0) boffs[NBK] = NE;
    } else if (t < 256) {
        const float* W = (blockIdx.x == 2) ? W2 : W1;
        unsigned short* WtHi = wtbuf + (size_t)(blockIdx.x - 1) * 8192;
        unsigned short* WtLo = WtHi + 4096;
        int n = t >> 2, k0 = (t & 3) * 16;
        unsigned short hi[16], lo[16];
#pragma unroll
        for (int i = 0; i < 16; ++i) {
            float v = W[(k0 + i) * 64 + n];
            hi[i] = f2b(v);
            lo[i] = f2b(v - b2f(hi[i]));
        }
        ((uint4*)WtHi)[n * 8 + (t & 3) * 2]     = pack8(hi);
        ((uint4*)WtHi)[n * 8 + (t & 3) * 2 + 1] = pack8(hi + 8);
        ((uint4*)WtLo)[n * 8 + (t & 3) * 2]     = pack8(lo);
        ((uint4*)WtLo)[n * 8 + (t & 3) * 2 + 1] = pack8(lo + 8);
    }
}

// binning with precomputed bases (local prefix + boffs): zero global atomics.
__global__ __launch_bounds__(512) void
k_bin(const int* __restrict__ src, const int* __restrict__ dst,
      const int* __restrict__ cntmat, const int* __restrict__ boffs,
      int* __restrict__ ebuf) {
    __shared__ int lcnt[NBK];
    __shared__ int lbase[NBK];
    int t = threadIdx.x;
    long base = (long)blockIdx.x * CHUNK;
    for (int b = t; b < NBK; b += 512) lcnt[b] = 0;
    __syncthreads();
    int pk[8], bk[8], of[8];
#pragma unroll
    for (int j = 0; j < 8; ++j) {
        long i = base + j * 512 + t;
        if (i < NE) {
            int d = dst[i];
            bk[j] = d >> 7;
            pk[j] = src[i] * BKT + (d & (BKT - 1));
            of[j] = atomicAdd(&lcnt[bk[j]], 1);
        } else bk[j] = -1;
    }
    __syncthreads();
    for (int b = t; b < NBK; b += 512)
        lbase[b] = cntmat[blockIdx.x * NBK + b] + boffs[b];
    __syncthreads();
#pragma unroll
    for (int j = 0; j < 8; ++j)
        if (bk[j] >= 0) ebuf[lbase[bk[j]] + of[j]] = pk[j];
}

// per-bucket: LDS histogram of local idx -> rowptr/dinv, then exact CSR scatter
__global__ __launch_bounds__(512) void
k_csrdeg(const int* __restrict__ boffs, const int* __restrict__ ebuf,
         int* __restrict__ rowptr, float* __restrict__ dinv, int* __restrict__ csr) {
    __shared__ int hist[BKT];
    __shared__ int sc[BKT];
    __shared__ int lcur[BKT];
    int b = blockIdx.x, t = threadIdx.x;
    if (t < BKT) hist[t] = 0;
    __syncthreads();
    int beg = boffs[b], end = boffs[b + 1];
    for (int e = beg + t; e < end; e += 512)
        atomicAdd(&hist[ebuf[e] & (BKT - 1)], 1);
    __syncthreads();
    if (t < BKT) sc[t] = hist[t];
    __syncthreads();
    for (int o = 1; o < BKT; o <<= 1) {
        int a = (t < BKT && t >= o) ? sc[t - o] : 0;
        __syncthreads();
        if (t < BKT) sc[t] += a;
        __syncthreads();
    }
    int v0 = b * BKT;
    if (t < BKT) {
        int v = v0 + t;
        if (v < NN) {
            int excl = beg + sc[t] - hist[t];
            rowptr[v] = excl;
            dinv[v]   = rsqrtf((float)(hist[t] + 1));
            lcur[t]   = excl;
        }
    }
    if (b == NBK - 1 && t == 0) rowptr[NN] = NE;
    __syncthreads();
    for (int e = beg + t; e < end; e += 512) {
        int p = ebuf[e];
        int slot = atomicAdd(&lcur[p & (BKT - 1)], 1);
        csr[slot] = p >> 7;
    }
}

// MFMA matmul: out[n][:] = bf16(dinv[n] * (A[n][:] @ W)), 64 nodes/block.
// Split-bf16: A@W = Ahi·Whi + Ahi·Wlo (+ Alo·Whi if SPLIT_A) — ~f32 accurate.
template <bool SPLIT_A>
__global__ __launch_bounds__(256) void
k_mm_mfma(const void* __restrict__ Ain, const unsigned short* __restrict__ wt,
          const float* __restrict__ dinv, uint4* __restrict__ out) {
    __shared__ unsigned short smem[4 * 64 * 72];   // 36864 B
    unsigned short* Ahi  = smem;
    unsigned short* Alo  = smem + 4608;
    unsigned short* WtHi = smem + 9216;
    unsigned short* WtLo = smem + 13824;
    int t = threadIdx.x;
    int r = t >> 2, cc = t & 3, c0 = cc * 16;
    long n0 = (long)blockIdx.x * 64;
    {   // stage Wt (hi/lo), coalesced
        const uint4* H = (const uint4*)wt;
        const uint4* L = (const uint4*)(wt + 4096);
        uint4* dh = (uint4*)&WtHi[r * 72 + c0];
        uint4* dl = (uint4*)&WtLo[r * 72 + c0];
        dh[0] = H[r * 8 + cc * 2]; dh[1] = H[r * 8 + cc * 2 + 1];
        dl[0] = L[r * 8 + cc * 2]; dl[1] = L[r * 8 + cc * 2 + 1];
    }
    {   // stage A (convert+split if f32 input)
        long n = n0 + r; if (n >= NN) n = NN - 1;
        if constexpr (SPLIT_A) {
            const float4* X = (const float4*)Ain;
            unsigned short hi[16], lo[16];
#pragma unroll
            for (int i = 0; i < 4; ++i) {
                float4 v = X[n * 16 + cc * 4 + i];
                float vv[4] = {v.x, v.y, v.z, v.w};
#pragma unroll
                for (int j = 0; j < 4; ++j) {
                    unsigned short h = f2b(vv[j]);
                    hi[i * 4 + j] = h;
                    lo[i * 4 + j] = f2b(vv[j] - b2f(h));
                }
            }
            uint4* dh = (uint4*)&Ahi[r * 72 + c0];
            uint4* dl = (uint4*)&Alo[r * 72 + c0];
            dh[0] = pack8(hi); dh[1] = pack8(hi + 8);
            dl[0] = pack8(lo); dl[1] = pack8(lo + 8);
        } else {
            const uint4* X = (const uint4*)Ain;
            uint4* dh = (uint4*)&Ahi[r * 72 + c0];
            dh[0] = X[n * 8 + cc * 2]; dh[1] = X[n * 8 + cc * 2 + 1];
        }
    }
    __syncthreads();
    int lane = t & 63, w = t >> 6;
    int q = lane >> 4, m = lane & 15;
    f32x4 acc[4] = {{0.f,0.f,0.f,0.f},{0.f,0.f,0.f,0.f},{0.f,0.f,0.f,0.f},{0.f,0.f,0.f,0.f}};
#pragma unroll
    for (int s = 0; s < 2; ++s) {
        int ko = s * 32 + q * 8;
        bf16x8 ah = *(const bf16x8*)&Ahi[(w * 16 + m) * 72 + ko];
        bf16x8 al{};
        if constexpr (SPLIT_A) al = *(const bf16x8*)&Alo[(w * 16 + m) * 72 + ko];
#pragma unroll
        for (int c = 0; c < 4; ++c) {
            bf16x8 bh = *(const bf16x8*)&WtHi[(c * 16 + m) * 72 + ko];
            bf16x8 bl = *(const bf16x8*)&WtLo[(c * 16 + m) * 72 + ko];
            acc[c] = __builtin_amdgcn_mfma_f32_16x16x32_bf16(ah, bh, acc[c], 0, 0, 0);
            acc[c] = __builtin_amdgcn_mfma_f32_16x16x32_bf16(ah, bl, acc[c], 0, 0, 0);
            if constexpr (SPLIT_A)
                acc[c] = __builtin_amdgcn_mfma_f32_16x16x32_bf16(al, bh, acc[c], 0, 0, 0);
        }
    }
    __syncthreads();
    float* Ct = (float*)smem;   // 64 x 68 f32 tile (17408 B, overlaps dead A/Wt)
#pragma unroll
    for (int c = 0; c < 4; ++c)
#pragma unroll
        for (int rr = 0; rr < 4; ++rr)
            Ct[(w * 16 + q * 4 + rr) * 68 + c * 16 + m] = acc[c][rr];
    __syncthreads();
    {
        long n = n0 + r;
        if (n < NN) {
            float dv = dinv[n];
            unsigned short ob[16];
#pragma unroll
            for (int i = 0; i < 4; ++i) {
                float4 v = *(const float4*)&Ct[r * 68 + c0 + i * 4];
                ob[i * 4 + 0] = f2b(v.x * dv); ob[i * 4 + 1] = f2b(v.y * dv);
                ob[i * 4 + 2] = f2b(v.z * dv); ob[i * 4 + 3] = f2b(v.w * dv);
            }
            out[n * 8 + cc * 2]     = pack8(ob);
            out[n * 8 + cc * 2 + 1] = pack8(ob + 8);
        }
    }
}

// CSR pull aggregation on bf16 rows. lane = slot(3b) x fg(3b); each lane gathers
// uint4 = 8 bf16 (16 B). One node per slot; unroll 8 for MLP. RELU=true: layer1.
template <bool RELU>
__global__ __launch_bounds__(256) void
k_agg(const int* __restrict__ rowptr, const int* __restrict__ csr,
      const uint4* __restrict__ g4, const float* __restrict__ dinv,
      const float* __restrict__ bias, uint4* __restrict__ out4) {
    int t = threadIdx.x;
    int lane = t & 63;
    int fg = lane & 7;           // dims [fg*8, fg*8+8)
    int slot = lane >> 3;        // 0..7
    int wid = blockIdx.x * 4 + (t >> 6);
    int v = wid * 8 + slot;      // 12500 * 8 == NN exactly
    int beg = rowptr[v];
    int len = rowptr[v + 1] - beg;
    int lmax = len;
    lmax = max(lmax, __shfl_xor(lmax, 8));
    lmax = max(lmax, __shfl_xor(lmax, 16));
    lmax = max(lmax, __shfl_xor(lmax, 32));
    float acc[8];
    {   // self-loop term
        uint4 sv = g4[(long)v * 8 + fg];
        acc[0] = __uint_as_float(sv.x << 16); acc[1] = __uint_as_float(sv.x & 0xFFFF0000u);
        acc[2] = __uint_as_float(sv.y << 16); acc[3] = __uint_as_float(sv.y & 0xFFFF0000u);
        acc[4] = __uint_as_float(sv.z << 16); acc[5] = __uint_as_float(sv.z & 0xFFFF0000u);
        acc[6] = __uint_as_float(sv.w << 16); acc[7] = __uint_as_float(sv.w & 0xFFFF0000u);
    }
    for (int e = 0; e < lmax; e += 8) {
#pragma unroll
        for (int j = 0; j < 8; ++j) {
            int ee = e + j;
            float m = (ee < len) ? 1.f : 0.f;
            int idx = beg + ((ee < len) ? ee : 0);
            int srcn = csr[idx];
            uint4 a = g4[(long)srcn * 8 + fg];
            acc[0] += m * __uint_as_float(a.x << 16);
            acc[1] += m * __uint_as_float(a.x & 0xFFFF0000u);
            acc[2] += m * __uint_as_float(a.y << 16);
            acc[3] += m * __uint_as_float(a.y & 0xFFFF0000u);
            acc[4] += m * __uint_as_float(a.z << 16);
            acc[5] += m * __uint_as_float(a.z & 0xFFFF0000u);
            acc[6] += m * __uint_as_float(a.w << 16);
            acc[7] += m * __uint_as_float(a.w & 0xFFFF0000u);
        }
    }
    float dv = dinv[v];
    unsigned short ob[8];
#pragma unroll
    for (int k = 0; k < 8; ++k) {
        float x = acc[k] * dv + bias[fg * 8 + k];
        if (RELU) x = fmaxf(x, 0.f);
        ob[k] = f2b(x);
    }
    out4[(long)v * 8 + fg] = pack8(ob);
}

// fused mean-pool + MLP head, one wave per graph, zero atomics (batch sorted)
__global__ void k_poolhead(const unsigned short* __restrict__ h,
                           const int* __restrict__ batch,
                           const float* __restrict__ lw1, const float* __restrict__ lb1,
                           const float* __restrict__ lw2, const float* __restrict__ lb2,
                           float* __restrict__ out) {
    __shared__ float pl[D];
    __shared__ float z[DH];
    int g = blockIdx.x;
    int t = threadIdx.x;  // 64, lane = dim
    int lo = 0, hi = NN;
    while (lo < hi) { int m = (lo + hi) >> 1; if (batch[m] < g) lo = m + 1; else hi = m; }
    int lb = lo;
    hi = NN;
    while (lo < hi) { int m = (lo + hi) >> 1; if (batch[m] < g + 1) lo = m + 1; else hi = m; }
    int ub = lo;
    float s = 0.f;
    int n = lb;
    for (; n + 4 <= ub; n += 4) {
        float a0 = b2f(h[(long)(n + 0) * D + t]);
        float a1 = b2f(h[(long)(n + 1) * D + t]);
        float a2 = b2f(h[(long)(n + 2) * D + t]);
        float a3 = b2f(h[(long)(n + 3) * D + t]);
        s += a0 + a1 + a2 + a3;
    }
    for (; n < ub; ++n) s += b2f(h[(long)n * D + t]);
    pl[t] = s / fmaxf((float)(ub - lb), 1.0f);
    __syncthreads();
    if (t < DH) {
        float a = lb1[t];
#pragma unroll
        for (int k = 0; k < D; ++k) a += pl[k] * lw1[k * DH + t];
        z[t] = fmaxf(a, 0.f);
    }
    __syncthreads();
    if (t < DO) {
        float a = lb2[t];
#pragma unroll
        for (int j = 0; j < DH; ++j) a += z[j] * lw2[j * DO + t];
        out[g * DO + t] = a;
    }
}

extern "C" void kernel_launch(void* const* d_in, const int* in_sizes, int n_in,
                              void* d_out, int out_size, void* d_ws, size_t ws_size,
                              hipStream_t stream) {
    const float* x    = (const float*)d_in[0];
    const int*   ei   = (const int*)  d_in[1];
    const int*   batch= (const int*)  d_in[2];
    const float* W1   = (const float*)d_in[3];
    const float* b1   = (const float*)d_in[4];
    const float* W2   = (const float*)d_in[5];
    const float* b2   = (const float*)d_in[6];
    const float* lw1  = (const float*)d_in[7];
    const float* lb1  = (const float*)d_in[8];
    const float* lw2  = (const float*)d_in[9];
    const float* lb2  = (const float*)d_in[10];
    float* out = (float*)d_out;

    const int* srcv = ei;        // edge_index[0]
    const int* dstv = ei + NE;   // edge_index[1]

    char* ws = (char*)d_ws;
    size_t off = 0;
    auto alloc = [&](size_t bytes) {
        void* p = ws + off;
        off = (off + bytes + 255) & ~(size_t)255;
        return p;
    };
    int*   cntmat = (int*)  alloc((size_t)NCH * NBK * 4);  // 1.22 MB
    int*   bsum   = (int*)  alloc((size_t)NBK * 4);
    int*   boffs  = (int*)  alloc((size_t)(NBK + 1) * 4);
    int*   rowptr = (int*)  alloc((size_t)(NN + 1) * 4);
    int*   csr    = (int*)  alloc((size_t)NE * 4);         // 6.4 MB
    float* dinv   = (float*)alloc((size_t)NN * 4);
    unsigned short* wtbuf = (unsigned short*)alloc((size_t)4 * 4096 * 2);  // 32 KB
    unsigned short* bufA = (unsigned short*)alloc((size_t)NN * D * 2);    // 12.8 MB
    unsigned short* bufB = (unsigned short*)alloc((size_t)NN * D * 2);    // 12.8 MB
    int*   ebuf   = (int*)bufA;  // binning scratch (6.4 MB); dead before bufA written

    k_hist          <<<NCH, 512, 0, stream>>>(dstv, cntmat);
    k_colsum_rowscan<<<NBK, 512, 0, stream>>>(cntmat, bsum);
    k_scan_prepw    <<<3, 1024, 0, stream>>>(bsum, boffs, W1, W2, wtbuf);
    k_bin           <<<NCH, 512, 0, stream>>>(srcv, dstv, cntmat, boffs, ebuf);
    k_csrdeg        <<<NBK, 512, 0, stream>>>(boffs, ebuf, rowptr, dinv, csr);

    const int MMB = (NN + 63) / 64;   // 1563

    // layer 1: g1 = bf16((x @ W1) * dinv) -> bufA ; h1 = relu(agg) -> bufB
    k_mm_mfma<true><<<MMB, 256, 0, stream>>>(x, wtbuf, dinv, (uint4*)bufA);
    k_agg<true><<<NN / 32, 256, 0, stream>>>(
        rowptr, csr, (const uint4*)bufA, dinv, b1, (uint4*)bufB);

    // layer 2: g2 = bf16((h1 @ W2) * dinv) -> bufA ; h2 = agg -> bufB
    k_mm_mfma<false><<<MMB, 256, 0, stream>>>(bufB, wtbuf + 8192, dinv, (uint4*)bufA);
    k_agg<false><<<NN / 32, 256, 0, stream>>>(
        rowptr, csr, (const uint4*)bufA, dinv, b2, (uint4*)bufB);

    k_poolhead<<<NG, 64, 0, stream>>>(bufB, batch, lw1, lb1, lw2, lb2, out);
}